// Round 1
// 609.638 us; speedup vs baseline: 1.3790x; 1.3790x over previous
//
#include <hip/hip_runtime.h>

#define DD 128
#define SCAN_TILE 1024   // 256 threads x 4 elements per block

// ---------------- CSR-build path (no float atomics) ----------------

// Histogram edge destinations for both directions in one launch.
__global__ __launch_bounds__(256) void count_kernel(
    const int* __restrict__ dst1, int E1, int* deg1,
    const int* __restrict__ dst2, int E2, int* deg2)
{
    int t = blockIdx.x * 256 + threadIdx.x;
    if (t < E1) {
        atomicAdd(deg1 + dst1[t], 1);
    } else if (t - E1 < E2) {
        atomicAdd(deg2 + dst2[t - E1], 1);
    }
}

// ---- Multi-block exclusive scan over the two degree arrays ----
// Phase A: per-block tile sums. Blocks [0,nb0) cover items, [nb0,nb0+nb1) users.
__global__ __launch_bounds__(256) void scanA_kernel(
    const int* __restrict__ cur_i, int NI,
    const int* __restrict__ cur_u, int NU,
    int* bsum, int nb0)
{
    int b = blockIdx.x;
    const int* cur;
    int N, base;
    if (b < nb0) { cur = cur_i; N = NI; base = b * SCAN_TILE; }
    else         { cur = cur_u; N = NU; base = (b - nb0) * SCAN_TILE; }
    int t = threadIdx.x;
    int idx0 = base + t * 4;
    int s = 0;
    #pragma unroll
    for (int k = 0; k < 4; ++k) {
        int idx = idx0 + k;
        if (idx < N) s += cur[idx];
    }
    __shared__ int red[256];
    red[t] = s;
    __syncthreads();
    for (int o = 128; o >= 1; o >>= 1) {
        if (t < o) red[t] += red[t + o];
        __syncthreads();
    }
    if (t == 0) bsum[b] = red[0];
}

// In-place exclusive scan of a[0..n) by one 256-thread block; returns total.
__device__ int block_exscan_inplace(int* a, int n)
{
    __shared__ int sh[256];
    int t = threadIdx.x;
    int carry = 0;
    for (int base = 0; base < n; base += 256) {
        int v = (base + t < n) ? a[base + t] : 0;
        sh[t] = v;
        __syncthreads();
        for (int off = 1; off < 256; off <<= 1) {
            int u = (t >= off) ? sh[t - off] : 0;
            __syncthreads();
            sh[t] += u;
            __syncthreads();
        }
        if (base + t < n) a[base + t] = carry + sh[t] - v;  // exclusive
        int csum = sh[255];
        __syncthreads();
        carry += csum;
    }
    return carry;
}

// Phase B: one block scans the block sums of both segments; writes totals.
__global__ __launch_bounds__(256) void scanB_kernel(
    int* bsum, int nb0, int nb1,
    int* row_i, int NI, int* row_u, int NU)
{
    int tot0 = block_exscan_inplace(bsum, nb0);
    __syncthreads();
    int tot1 = block_exscan_inplace(bsum + nb0, nb1);
    if (threadIdx.x == 0) {
        row_i[NI] = tot0;
        row_u[NU] = tot1;
    }
}

// Phase C: per-block local exclusive scan + block offset; writes row & cur.
__global__ __launch_bounds__(256) void scanC_kernel(
    int* cur_i, int* row_i, int NI,
    int* cur_u, int* row_u, int NU,
    const int* __restrict__ bsum, int nb0)
{
    int b = blockIdx.x;
    int off = bsum[b];
    int* cur; int* row;
    int N, base;
    if (b < nb0) { cur = cur_i; row = row_i; N = NI; base = b * SCAN_TILE; }
    else         { cur = cur_u; row = row_u; N = NU; base = (b - nb0) * SCAN_TILE; }
    int t = threadIdx.x;
    int idx0 = base + t * 4;
    int v[4];
    int s = 0;
    #pragma unroll
    for (int k = 0; k < 4; ++k) {
        int idx = idx0 + k;
        v[k] = (idx < N) ? cur[idx] : 0;
        s += v[k];
    }
    __shared__ int sh[256];
    sh[t] = s;
    __syncthreads();
    for (int o = 1; o < 256; o <<= 1) {
        int u = (t >= o) ? sh[t - o] : 0;
        __syncthreads();
        sh[t] += u;
        __syncthreads();
    }
    int run = off + sh[t] - s;   // exclusive prefix of this thread's first elem
    #pragma unroll
    for (int k = 0; k < 4; ++k) {
        int idx = idx0 + k;
        if (idx < N) {
            row[idx] = run;
            cur[idx] = run;   // cursor = start position for fill
            run += v[k];
        }
    }
}

// Scatter edge ids into destination-grouped order (both directions).
__global__ __launch_bounds__(256) void fill_kernel(
    const int* __restrict__ dst1, int E1, int* cur1, int* perm1,
    const int* __restrict__ dst2, int E2, int* cur2, int* perm2)
{
    int t = blockIdx.x * 256 + threadIdx.x;
    if (t < E1) {
        int pos = atomicAdd(cur1 + dst1[t], 1);
        perm1[pos] = t;
    } else if (t - E1 < E2) {
        int e = t - E1;
        int pos = atomicAdd(cur2 + dst2[e], 1);
        perm2[pos] = e;
    }
}

// One wave per destination node; first NI waves = items (dir u2i),
// next NU waves = users (dir i2u). Gathers norm-weighted source rows,
// writes agg (aliases d_out) and ssum. No atomics.
__global__ __launch_bounds__(256) void gather_kernel(
    const int* __restrict__ row_i, const int* __restrict__ perm1,
    const int* __restrict__ src1,  const float* __restrict__ norm1,
    const float* __restrict__ feat_user, float* agg_item, float* ssum_i, int NI,
    const int* __restrict__ row_u, const int* __restrict__ perm2,
    const int* __restrict__ src2,  const float* __restrict__ norm2,
    const float* __restrict__ feat_item, float* agg_user, float* ssum_u, int NU)
{
    int gw = (int)((blockIdx.x * 256u + threadIdx.x) >> 6);
    int lane = threadIdx.x & 63;
    if (gw >= NI + NU) return;

    const int *row, *perm, *src;
    const float *norm, *feat;
    float *agg, *ssum;
    int d;
    if (gw < NI) {
        d = gw;      row = row_i; perm = perm1; src = src1; norm = norm1;
        feat = feat_user; agg = agg_item; ssum = ssum_i;
    } else {
        d = gw - NI; row = row_u; perm = perm2; src = src2; norm = norm2;
        feat = feat_item; agg = agg_user; ssum = ssum_u;
    }

    int beg = row[d], end = row[d + 1];
    float2 acc = {0.f, 0.f};
    float sn = 0.f;
    int j = beg;
    for (; j + 1 < end; j += 2) {           // unroll 2 for load ILP
        int e0 = perm[j], e1 = perm[j + 1];
        int s0 = src[e0], s1 = src[e1];
        float n0 = norm[e0], n1 = norm[e1];
        float2 v0 = *(const float2*)(feat + (size_t)s0 * DD + lane * 2);
        float2 v1 = *(const float2*)(feat + (size_t)s1 * DD + lane * 2);
        acc.x += n0 * v0.x + n1 * v1.x;
        acc.y += n0 * v0.y + n1 * v1.y;
        sn += n0 + n1;
    }
    if (j < end) {
        int e0 = perm[j];
        int s0 = src[e0];
        float n0 = norm[e0];
        float2 v0 = *(const float2*)(feat + (size_t)s0 * DD + lane * 2);
        acc.x += n0 * v0.x;
        acc.y += n0 * v0.y;
        sn += n0;
    }
    *(float2*)(agg + (size_t)d * DD + lane * 2) = acc;
    if (lane == 0) ssum[d] = sn;
}

// ---------------- Fallback: atomic scatter (proven in R3) ----------------

__global__ __launch_bounds__(256) void scatter_kernel(
    const float* __restrict__ feat_src,
    const int* __restrict__ src,
    const int* __restrict__ dst,
    const float* __restrict__ norm,
    float* agg,
    float* ssum,
    int E)
{
    int gw = (int)((blockIdx.x * 256u + threadIdx.x) >> 6);
    int lane = threadIdx.x & 63;
    if (gw >= E) return;
    int si = src[gw];
    int di = dst[gw];
    float nv = norm[gw];
    float2 v = *(const float2*)(feat_src + (size_t)si * DD + lane * 2);
    float* ap = agg + (size_t)di * DD + lane * 2;
    unsafeAtomicAdd(ap,     v.x * nv);
    unsafeAtomicAdd(ap + 1, v.y * nv);
    if (lane == 0) unsafeAtomicAdd(ssum + di, nv);
}

// ---------------- Finish: h = (f+a)@W1 + (f*a)@W2 + bias, lrelu, l2norm ----

// Per block: 16 rows. agg ALIASES out: rows staged to LDS before overwrite.
__global__ __launch_bounds__(256) void finish_kernel(
    const float* __restrict__ feat,
    const float* agg,
    const float* __restrict__ ssum,
    const float* __restrict__ W1,
    const float* __restrict__ b1,
    const float* __restrict__ W2,
    const float* __restrict__ b2,
    float* out,
    int nrows)
{
    __shared__ float xs[16][DD];
    __shared__ float ys[16][DD];
    int row0 = blockIdx.x * 16;
    int tid = threadIdx.x;

    for (int i = tid; i < 16 * (DD / 4); i += 256) {
        int r = i >> 5;
        int c4 = (i & 31) * 4;
        int row = row0 + r;
        if (row < nrows) {
            float4 f = *(const float4*)(feat + (size_t)row * DD + c4);
            float4 a = *(const float4*)(agg  + (size_t)row * DD + c4);
            float4 x, y;
            x.x = f.x + a.x; x.y = f.y + a.y; x.z = f.z + a.z; x.w = f.w + a.w;
            y.x = f.x * a.x; y.y = f.y * a.y; y.z = f.z * a.z; y.w = f.w * a.w;
            *(float4*)&xs[r][c4] = x;
            *(float4*)&ys[r][c4] = y;
        }
    }
    __syncthreads();

    int c0 = tid & 63;
    int rg = tid >> 6;
    int c1 = c0 + 64;

    float acc[4][2] = {{0.f,0.f},{0.f,0.f},{0.f,0.f},{0.f,0.f}};
    for (int k = 0; k < DD; k += 4) {
        float w1a[4], w1b[4], w2a[4], w2b[4];
        #pragma unroll
        for (int kk = 0; kk < 4; ++kk) {
            const float* wr1 = W1 + (size_t)(k + kk) * DD;
            const float* wr2 = W2 + (size_t)(k + kk) * DD;
            w1a[kk] = wr1[c0]; w1b[kk] = wr1[c1];
            w2a[kk] = wr2[c0]; w2b[kk] = wr2[c1];
        }
        #pragma unroll
        for (int r = 0; r < 4; ++r) {
            float4 xv = *(const float4*)&xs[rg * 4 + r][k];
            float4 yv = *(const float4*)&ys[rg * 4 + r][k];
            acc[r][0] += xv.x*w1a[0] + xv.y*w1a[1] + xv.z*w1a[2] + xv.w*w1a[3]
                       + yv.x*w2a[0] + yv.y*w2a[1] + yv.z*w2a[2] + yv.w*w2a[3];
            acc[r][1] += xv.x*w1b[0] + xv.y*w1b[1] + xv.z*w1b[2] + xv.w*w1b[3]
                       + yv.x*w2b[0] + yv.y*w2b[1] + yv.z*w2b[2] + yv.w*w2b[3];
        }
    }

    float b1c0 = b1[c0], b1c1 = b1[c1];
    float b2c0 = b2[c0], b2c1 = b2[c1];

    #pragma unroll
    for (int r = 0; r < 4; ++r) {
        int row = row0 + rg * 4 + r;
        if (row < nrows) {
            float s = ssum[row];
            float h0 = acc[r][0] + (1.0f + s) * b1c0 + s * b2c0;
            float h1 = acc[r][1] + (1.0f + s) * b1c1 + s * b2c1;
            h0 = h0 >= 0.f ? h0 : 0.2f * h0;
            h1 = h1 >= 0.f ? h1 : 0.2f * h1;
            float loc = h0 * h0 + h1 * h1;
            #pragma unroll
            for (int m = 32; m >= 1; m >>= 1) loc += __shfl_xor(loc, m, 64);
            float inv = 1.0f / fmaxf(sqrtf(loc), 1e-12f);
            out[(size_t)row * DD + c0] = h0 * inv;
            out[(size_t)row * DD + c1] = h1 * inv;
        }
    }
}

extern "C" void kernel_launch(void* const* d_in, const int* in_sizes, int n_in,
                              void* d_out, int out_size, void* d_ws, size_t ws_size,
                              hipStream_t stream) {
    const float* feat_user = (const float*)d_in[0];
    const float* feat_item = (const float*)d_in[1];
    const float* W1        = (const float*)d_in[2];
    const float* b1        = (const float*)d_in[3];
    const float* W2        = (const float*)d_in[4];
    const float* b2        = (const float*)d_in[5];
    const float* norm_u2i  = (const float*)d_in[6];
    const float* norm_i2u  = (const float*)d_in[7];
    const int* eus = (const int*)d_in[8];
    const int* eud = (const int*)d_in[9];
    const int* eis = (const int*)d_in[10];
    const int* eid = (const int*)d_in[11];

    int NU = in_sizes[0] / DD;
    int NI = in_sizes[1] / DD;
    int E1 = in_sizes[8];
    int E2 = in_sizes[10];
    float* out = (float*)d_out;

    // agg aliases d_out (exactly (NU+NI)*DD floats).
    float* agg_user = out;
    float* agg_item = out + (size_t)NU * DD;

    int nb0 = (NI + SCAN_TILE - 1) / SCAN_TILE;
    int nb1 = (NU + SCAN_TILE - 1) / SCAN_TILE;

    size_t need = ((size_t)3 * NU + 3 * NI + E1 + E2 + 2
                   + nb0 + nb1) * sizeof(int);

    if (ws_size >= need) {
        // ---- CSR gather path (no float atomics) ----
        int* cur_i = (int*)d_ws;            // NI   (deg -> cursor, dir u2i)
        int* cur_u = cur_i + NI;            // NU   (deg -> cursor, dir i2u)
        int* row_i = cur_u + NU;            // NI+1
        int* row_u = row_i + NI + 1;        // NU+1
        int* perm1 = row_u + NU + 1;        // E1 (u2i edge ids grouped by item)
        int* perm2 = perm1 + E1;            // E2 (i2u edge ids grouped by user)
        float* ssum_i = (float*)(perm2 + E2);  // NI
        float* ssum_u = ssum_i + NI;           // NU
        int* bsum = (int*)(ssum_u + NU);       // nb0+nb1 block sums

        hipMemsetAsync(d_ws, 0, (size_t)(NI + NU) * sizeof(int), stream);

        int eb = (int)(((long long)E1 + E2 + 255) / 256);
        count_kernel<<<eb, 256, 0, stream>>>(eud, E1, cur_i, eid, E2, cur_u);

        // 3-phase multi-block exclusive scan (replaces the 2-block serial scan:
        // that one ran at 0.22% occupancy and cost ~255 us of the 840 us total).
        scanA_kernel<<<nb0 + nb1, 256, 0, stream>>>(cur_i, NI, cur_u, NU,
                                                    bsum, nb0);
        scanB_kernel<<<1, 256, 0, stream>>>(bsum, nb0, nb1,
                                            row_i, NI, row_u, NU);
        scanC_kernel<<<nb0 + nb1, 256, 0, stream>>>(cur_i, row_i, NI,
                                                    cur_u, row_u, NU,
                                                    bsum, nb0);

        fill_kernel<<<eb, 256, 0, stream>>>(eud, E1, cur_i, perm1,
                                            eid, E2, cur_u, perm2);

        int gb = (int)(((long long)(NI + NU) * 64 + 255) / 256);
        gather_kernel<<<gb, 256, 0, stream>>>(
            row_i, perm1, eus, norm_u2i, feat_user, agg_item, ssum_i, NI,
            row_u, perm2, eis, norm_i2u, feat_item, agg_user, ssum_u, NU);

        finish_kernel<<<(NU + 15) / 16, 256, 0, stream>>>(
            feat_user, agg_user, ssum_u, W1, b1, W2, b2, out, NU);
        finish_kernel<<<(NI + 15) / 16, 256, 0, stream>>>(
            feat_item, agg_item, ssum_i, W1, b1, W2, b2,
            out + (size_t)NU * DD, NI);
    } else {
        // ---- Fallback: R3 atomic path ----
        float* s_user = (float*)d_ws;
        float* s_item = s_user + NU;

        hipMemsetAsync(out, 0, (size_t)out_size * sizeof(float), stream);
        hipMemsetAsync(d_ws, 0, (size_t)(NU + NI) * sizeof(float), stream);

        int b1n = (int)(((long long)E1 * 64 + 255) / 256);
        scatter_kernel<<<b1n, 256, 0, stream>>>(feat_user, eus, eud, norm_u2i,
                                                agg_item, s_item, E1);
        int b2n = (int)(((long long)E2 * 64 + 255) / 256);
        scatter_kernel<<<b2n, 256, 0, stream>>>(feat_item, eis, eid, norm_i2u,
                                                agg_user, s_user, E2);

        finish_kernel<<<(NU + 15) / 16, 256, 0, stream>>>(
            feat_user, agg_user, s_user, W1, b1, W2, b2, out, NU);
        finish_kernel<<<(NI + 15) / 16, 256, 0, stream>>>(
            feat_item, agg_item, s_item, W1, b1, W2, b2,
            out + (size_t)NU * DD, NI);
    }
}

// Round 2
// 526.632 us; speedup vs baseline: 1.5964x; 1.1576x over previous
//
#include <hip/hip_runtime.h>

#define DD 128
#define SCAN_TILE 1024   // 256 threads x 4 elements per block

// ---------------- CSR-build path (no float atomics) ----------------

// Histogram edge destinations for both directions in one launch.
__global__ __launch_bounds__(256) void count_kernel(
    const int* __restrict__ dst1, int E1, int* deg1,
    const int* __restrict__ dst2, int E2, int* deg2)
{
    int t = blockIdx.x * 256 + threadIdx.x;
    if (t < E1) {
        atomicAdd(deg1 + dst1[t], 1);
    } else if (t - E1 < E2) {
        atomicAdd(deg2 + dst2[t - E1], 1);
    }
}

// ---- Multi-block exclusive scan over the two degree arrays ----
// Phase A: per-block tile sums. Blocks [0,nb0) cover items, [nb0,nb0+nb1) users.
__global__ __launch_bounds__(256) void scanA_kernel(
    const int* __restrict__ cur_i, int NI,
    const int* __restrict__ cur_u, int NU,
    int* bsum, int nb0)
{
    int b = blockIdx.x;
    const int* cur;
    int N, base;
    if (b < nb0) { cur = cur_i; N = NI; base = b * SCAN_TILE; }
    else         { cur = cur_u; N = NU; base = (b - nb0) * SCAN_TILE; }
    int t = threadIdx.x;
    int idx0 = base + t * 4;
    int s = 0;
    #pragma unroll
    for (int k = 0; k < 4; ++k) {
        int idx = idx0 + k;
        if (idx < N) s += cur[idx];
    }
    __shared__ int red[256];
    red[t] = s;
    __syncthreads();
    for (int o = 128; o >= 1; o >>= 1) {
        if (t < o) red[t] += red[t + o];
        __syncthreads();
    }
    if (t == 0) bsum[b] = red[0];
}

// In-place exclusive scan of a[0..n) by one 256-thread block; returns total.
__device__ int block_exscan_inplace(int* a, int n)
{
    __shared__ int sh[256];
    int t = threadIdx.x;
    int carry = 0;
    for (int base = 0; base < n; base += 256) {
        int v = (base + t < n) ? a[base + t] : 0;
        sh[t] = v;
        __syncthreads();
        for (int off = 1; off < 256; off <<= 1) {
            int u = (t >= off) ? sh[t - off] : 0;
            __syncthreads();
            sh[t] += u;
            __syncthreads();
        }
        if (base + t < n) a[base + t] = carry + sh[t] - v;  // exclusive
        int csum = sh[255];
        __syncthreads();
        carry += csum;
    }
    return carry;
}

// Phase B: one block scans the block sums of both segments; writes totals.
__global__ __launch_bounds__(256) void scanB_kernel(
    int* bsum, int nb0, int nb1,
    int* row_i, int NI, int* row_u, int NU)
{
    int tot0 = block_exscan_inplace(bsum, nb0);
    __syncthreads();
    int tot1 = block_exscan_inplace(bsum + nb0, nb1);
    if (threadIdx.x == 0) {
        row_i[NI] = tot0;
        row_u[NU] = tot1;
    }
}

// Phase C: per-block local exclusive scan + block offset; writes row & cur.
__global__ __launch_bounds__(256) void scanC_kernel(
    int* cur_i, int* row_i, int NI,
    int* cur_u, int* row_u, int NU,
    const int* __restrict__ bsum, int nb0)
{
    int b = blockIdx.x;
    int off = bsum[b];
    int* cur; int* row;
    int N, base;
    if (b < nb0) { cur = cur_i; row = row_i; N = NI; base = b * SCAN_TILE; }
    else         { cur = cur_u; row = row_u; N = NU; base = (b - nb0) * SCAN_TILE; }
    int t = threadIdx.x;
    int idx0 = base + t * 4;
    int v[4];
    int s = 0;
    #pragma unroll
    for (int k = 0; k < 4; ++k) {
        int idx = idx0 + k;
        v[k] = (idx < N) ? cur[idx] : 0;
        s += v[k];
    }
    __shared__ int sh[256];
    sh[t] = s;
    __syncthreads();
    for (int o = 1; o < 256; o <<= 1) {
        int u = (t >= o) ? sh[t - o] : 0;
        __syncthreads();
        sh[t] += u;
        __syncthreads();
    }
    int run = off + sh[t] - s;   // exclusive prefix of this thread's first elem
    #pragma unroll
    for (int k = 0; k < 4; ++k) {
        int idx = idx0 + k;
        if (idx < N) {
            row[idx] = run;
            cur[idx] = run;   // cursor = start position for fill
            run += v[k];
        }
    }
}

// ---- Tier 1 fill: scatter PRE-GATHERED (src, norm) into dst-grouped order.
// Removes one indirection level from the gather's dependent-load chain.
__global__ __launch_bounds__(256) void fill_pg_kernel(
    const int* __restrict__ dst1, const int* __restrict__ src1,
    const float* __restrict__ norm1, int E1, int* cur1, int* ss1, float* ns1,
    const int* __restrict__ dst2, const int* __restrict__ src2,
    const float* __restrict__ norm2, int E2, int* cur2, int* ss2, float* ns2)
{
    int t = blockIdx.x * 256 + threadIdx.x;
    if (t < E1) {
        int pos = atomicAdd(cur1 + dst1[t], 1);
        ss1[pos] = src1[t];
        ns1[pos] = norm1[t];
    } else if (t - E1 < E2) {
        int e = t - E1;
        int pos = atomicAdd(cur2 + dst2[e], 1);
        ss2[pos] = src2[e];
        ns2[pos] = norm2[e];
    }
}

// Tier 1 gather: one wave per destination node. Chain is now
// srcs[j] (sequential, cached) -> feat row (random), 4 rows in flight.
// agg written non-temporally so 77 MB of output doesn't evict feat from L3.
__global__ __launch_bounds__(256) void gather_kernel(
    const int* __restrict__ row_i, const int* __restrict__ srcs1,
    const float* __restrict__ norms1,
    const float* __restrict__ feat_user, float* agg_item, float* ssum_i, int NI,
    const int* __restrict__ row_u, const int* __restrict__ srcs2,
    const float* __restrict__ norms2,
    const float* __restrict__ feat_item, float* agg_user, float* ssum_u, int NU)
{
    int gw = (int)((blockIdx.x * 256u + threadIdx.x) >> 6);
    int lane = threadIdx.x & 63;
    if (gw >= NI + NU) return;

    const int *row, *srcs;
    const float *norms, *feat;
    float *agg, *ssum;
    int d;
    if (gw < NI) {
        d = gw;      row = row_i; srcs = srcs1; norms = norms1;
        feat = feat_user; agg = agg_item; ssum = ssum_i;
    } else {
        d = gw - NI; row = row_u; srcs = srcs2; norms = norms2;
        feat = feat_item; agg = agg_user; ssum = ssum_u;
    }

    int beg = row[d], end = row[d + 1];
    float2 acc = {0.f, 0.f};
    float sn = 0.f;
    int j = beg;
    for (; j + 4 <= end; j += 4) {          // 4 feat rows in flight
        int s0 = srcs[j], s1 = srcs[j + 1], s2 = srcs[j + 2], s3 = srcs[j + 3];
        float n0 = norms[j],     n1 = norms[j + 1];
        float n2 = norms[j + 2], n3 = norms[j + 3];
        float2 v0 = *(const float2*)(feat + (size_t)s0 * DD + lane * 2);
        float2 v1 = *(const float2*)(feat + (size_t)s1 * DD + lane * 2);
        float2 v2 = *(const float2*)(feat + (size_t)s2 * DD + lane * 2);
        float2 v3 = *(const float2*)(feat + (size_t)s3 * DD + lane * 2);
        acc.x += n0 * v0.x + n1 * v1.x + n2 * v2.x + n3 * v3.x;
        acc.y += n0 * v0.y + n1 * v1.y + n2 * v2.y + n3 * v3.y;
        sn += n0 + n1 + n2 + n3;
    }
    for (; j < end; ++j) {
        int s0 = srcs[j];
        float n0 = norms[j];
        float2 v0 = *(const float2*)(feat + (size_t)s0 * DD + lane * 2);
        acc.x += n0 * v0.x;
        acc.y += n0 * v0.y;
        sn += n0;
    }
    float* ap = agg + (size_t)d * DD + lane * 2;
    __builtin_nontemporal_store(acc.x, ap);
    __builtin_nontemporal_store(acc.y, ap + 1);
    if (lane == 0) ssum[d] = sn;
}

// ---- Tier 2 (old perm-based CSR path, kept as workspace fallback) ----

__global__ __launch_bounds__(256) void fill_perm_kernel(
    const int* __restrict__ dst1, int E1, int* cur1, int* perm1,
    const int* __restrict__ dst2, int E2, int* cur2, int* perm2)
{
    int t = blockIdx.x * 256 + threadIdx.x;
    if (t < E1) {
        int pos = atomicAdd(cur1 + dst1[t], 1);
        perm1[pos] = t;
    } else if (t - E1 < E2) {
        int e = t - E1;
        int pos = atomicAdd(cur2 + dst2[e], 1);
        perm2[pos] = e;
    }
}

__global__ __launch_bounds__(256) void gather_perm_kernel(
    const int* __restrict__ row_i, const int* __restrict__ perm1,
    const int* __restrict__ src1,  const float* __restrict__ norm1,
    const float* __restrict__ feat_user, float* agg_item, float* ssum_i, int NI,
    const int* __restrict__ row_u, const int* __restrict__ perm2,
    const int* __restrict__ src2,  const float* __restrict__ norm2,
    const float* __restrict__ feat_item, float* agg_user, float* ssum_u, int NU)
{
    int gw = (int)((blockIdx.x * 256u + threadIdx.x) >> 6);
    int lane = threadIdx.x & 63;
    if (gw >= NI + NU) return;

    const int *row, *perm, *src;
    const float *norm, *feat;
    float *agg, *ssum;
    int d;
    if (gw < NI) {
        d = gw;      row = row_i; perm = perm1; src = src1; norm = norm1;
        feat = feat_user; agg = agg_item; ssum = ssum_i;
    } else {
        d = gw - NI; row = row_u; perm = perm2; src = src2; norm = norm2;
        feat = feat_item; agg = agg_user; ssum = ssum_u;
    }

    int beg = row[d], end = row[d + 1];
    float2 acc = {0.f, 0.f};
    float sn = 0.f;
    int j = beg;
    for (; j + 1 < end; j += 2) {
        int e0 = perm[j], e1 = perm[j + 1];
        int s0 = src[e0], s1 = src[e1];
        float n0 = norm[e0], n1 = norm[e1];
        float2 v0 = *(const float2*)(feat + (size_t)s0 * DD + lane * 2);
        float2 v1 = *(const float2*)(feat + (size_t)s1 * DD + lane * 2);
        acc.x += n0 * v0.x + n1 * v1.x;
        acc.y += n0 * v0.y + n1 * v1.y;
        sn += n0 + n1;
    }
    if (j < end) {
        int e0 = perm[j];
        int s0 = src[e0];
        float n0 = norm[e0];
        float2 v0 = *(const float2*)(feat + (size_t)s0 * DD + lane * 2);
        acc.x += n0 * v0.x;
        acc.y += n0 * v0.y;
        sn += n0;
    }
    *(float2*)(agg + (size_t)d * DD + lane * 2) = acc;
    if (lane == 0) ssum[d] = sn;
}

// ---------------- Tier 3 fallback: atomic scatter ----------------

__global__ __launch_bounds__(256) void scatter_kernel(
    const float* __restrict__ feat_src,
    const int* __restrict__ src,
    const int* __restrict__ dst,
    const float* __restrict__ norm,
    float* agg,
    float* ssum,
    int E)
{
    int gw = (int)((blockIdx.x * 256u + threadIdx.x) >> 6);
    int lane = threadIdx.x & 63;
    if (gw >= E) return;
    int si = src[gw];
    int di = dst[gw];
    float nv = norm[gw];
    float2 v = *(const float2*)(feat_src + (size_t)si * DD + lane * 2);
    float* ap = agg + (size_t)di * DD + lane * 2;
    unsafeAtomicAdd(ap,     v.x * nv);
    unsafeAtomicAdd(ap + 1, v.y * nv);
    if (lane == 0) unsafeAtomicAdd(ssum + di, nv);
}

// ---------------- Finish: h = (f+a)@W1 + (f*a)@W2 + bias, lrelu, l2norm ----

// Per block: 32 rows (was 16) — halves W1/W2 L2 re-read per row and doubles
// the FMA : W-load ratio of the inner loop. agg ALIASES out: rows staged to
// LDS before overwrite; each block reads/writes only its own 32 rows.
__global__ __launch_bounds__(256) void finish_kernel(
    const float* __restrict__ feat,
    const float* agg,
    const float* __restrict__ ssum,
    const float* __restrict__ W1,
    const float* __restrict__ b1,
    const float* __restrict__ W2,
    const float* __restrict__ b2,
    float* out,
    int nrows)
{
    __shared__ float xs[32][DD];
    __shared__ float ys[32][DD];
    int row0 = blockIdx.x * 32;
    int tid = threadIdx.x;

    for (int i = tid; i < 32 * (DD / 4); i += 256) {
        int r = i >> 5;
        int c4 = (i & 31) * 4;
        int row = row0 + r;
        if (row < nrows) {
            float4 f = *(const float4*)(feat + (size_t)row * DD + c4);
            float4 a = *(const float4*)(agg  + (size_t)row * DD + c4);
            float4 x, y;
            x.x = f.x + a.x; x.y = f.y + a.y; x.z = f.z + a.z; x.w = f.w + a.w;
            y.x = f.x * a.x; y.y = f.y * a.y; y.z = f.z * a.z; y.w = f.w * a.w;
            *(float4*)&xs[r][c4] = x;
            *(float4*)&ys[r][c4] = y;
        }
    }
    __syncthreads();

    int c0 = tid & 63;
    int rg = tid >> 6;
    int c1 = c0 + 64;

    float acc[8][2] = {{0.f,0.f},{0.f,0.f},{0.f,0.f},{0.f,0.f},
                       {0.f,0.f},{0.f,0.f},{0.f,0.f},{0.f,0.f}};
    for (int k = 0; k < DD; k += 4) {
        float w1a[4], w1b[4], w2a[4], w2b[4];
        #pragma unroll
        for (int kk = 0; kk < 4; ++kk) {
            const float* wr1 = W1 + (size_t)(k + kk) * DD;
            const float* wr2 = W2 + (size_t)(k + kk) * DD;
            w1a[kk] = wr1[c0]; w1b[kk] = wr1[c1];
            w2a[kk] = wr2[c0]; w2b[kk] = wr2[c1];
        }
        #pragma unroll
        for (int r = 0; r < 8; ++r) {
            float4 xv = *(const float4*)&xs[rg * 8 + r][k];
            float4 yv = *(const float4*)&ys[rg * 8 + r][k];
            acc[r][0] += xv.x*w1a[0] + xv.y*w1a[1] + xv.z*w1a[2] + xv.w*w1a[3]
                       + yv.x*w2a[0] + yv.y*w2a[1] + yv.z*w2a[2] + yv.w*w2a[3];
            acc[r][1] += xv.x*w1b[0] + xv.y*w1b[1] + xv.z*w1b[2] + xv.w*w1b[3]
                       + yv.x*w2b[0] + yv.y*w2b[1] + yv.z*w2b[2] + yv.w*w2b[3];
        }
    }

    float b1c0 = b1[c0], b1c1 = b1[c1];
    float b2c0 = b2[c0], b2c1 = b2[c1];

    #pragma unroll
    for (int r = 0; r < 8; ++r) {
        int row = row0 + rg * 8 + r;
        if (row < nrows) {
            float s = ssum[row];
            float h0 = acc[r][0] + (1.0f + s) * b1c0 + s * b2c0;
            float h1 = acc[r][1] + (1.0f + s) * b1c1 + s * b2c1;
            h0 = h0 >= 0.f ? h0 : 0.2f * h0;
            h1 = h1 >= 0.f ? h1 : 0.2f * h1;
            float loc = h0 * h0 + h1 * h1;
            #pragma unroll
            for (int m = 32; m >= 1; m >>= 1) loc += __shfl_xor(loc, m, 64);
            float inv = 1.0f / fmaxf(sqrtf(loc), 1e-12f);
            out[(size_t)row * DD + c0] = h0 * inv;
            out[(size_t)row * DD + c1] = h1 * inv;
        }
    }
}

extern "C" void kernel_launch(void* const* d_in, const int* in_sizes, int n_in,
                              void* d_out, int out_size, void* d_ws, size_t ws_size,
                              hipStream_t stream) {
    const float* feat_user = (const float*)d_in[0];
    const float* feat_item = (const float*)d_in[1];
    const float* W1        = (const float*)d_in[2];
    const float* b1        = (const float*)d_in[3];
    const float* W2        = (const float*)d_in[4];
    const float* b2        = (const float*)d_in[5];
    const float* norm_u2i  = (const float*)d_in[6];
    const float* norm_i2u  = (const float*)d_in[7];
    const int* eus = (const int*)d_in[8];
    const int* eud = (const int*)d_in[9];
    const int* eis = (const int*)d_in[10];
    const int* eid = (const int*)d_in[11];

    int NU = in_sizes[0] / DD;
    int NI = in_sizes[1] / DD;
    int E1 = in_sizes[8];
    int E2 = in_sizes[10];
    float* out = (float*)d_out;

    // agg aliases d_out (exactly (NU+NI)*DD floats).
    float* agg_user = out;
    float* agg_item = out + (size_t)NU * DD;

    int nb0 = (NI + SCAN_TILE - 1) / SCAN_TILE;
    int nb1 = (NU + SCAN_TILE - 1) / SCAN_TILE;

    size_t need_pg   = ((size_t)3 * NU + 3 * NI + 2 * E1 + 2 * E2 + 2
                        + nb0 + nb1) * sizeof(int);
    size_t need_perm = ((size_t)3 * NU + 3 * NI + E1 + E2 + 2
                        + nb0 + nb1) * sizeof(int);

    int eb = (int)(((long long)E1 + E2 + 255) / 256);
    int gb = (int)(((long long)(NI + NU) * 64 + 255) / 256);

    if (ws_size >= need_pg) {
        // ---- Tier 1: CSR + pre-gathered (src, norm) ----
        int* cur_i = (int*)d_ws;            // NI
        int* cur_u = cur_i + NI;            // NU
        int* row_i = cur_u + NU;            // NI+1
        int* row_u = row_i + NI + 1;        // NU+1
        int* ss1   = row_u + NU + 1;        // E1 (srcs, dst-grouped, u2i)
        int* ss2   = ss1 + E1;              // E2
        float* ns1 = (float*)(ss2 + E2);    // E1 (norms, dst-grouped)
        float* ns2 = ns1 + E1;              // E2
        float* ssum_i = ns2 + E2;           // NI
        float* ssum_u = ssum_i + NI;        // NU
        int* bsum = (int*)(ssum_u + NU);    // nb0+nb1

        hipMemsetAsync(d_ws, 0, (size_t)(NI + NU) * sizeof(int), stream);

        count_kernel<<<eb, 256, 0, stream>>>(eud, E1, cur_i, eid, E2, cur_u);
        scanA_kernel<<<nb0 + nb1, 256, 0, stream>>>(cur_i, NI, cur_u, NU,
                                                    bsum, nb0);
        scanB_kernel<<<1, 256, 0, stream>>>(bsum, nb0, nb1,
                                            row_i, NI, row_u, NU);
        scanC_kernel<<<nb0 + nb1, 256, 0, stream>>>(cur_i, row_i, NI,
                                                    cur_u, row_u, NU,
                                                    bsum, nb0);
        fill_pg_kernel<<<eb, 256, 0, stream>>>(
            eud, eus, norm_u2i, E1, cur_i, ss1, ns1,
            eid, eis, norm_i2u, E2, cur_u, ss2, ns2);

        gather_kernel<<<gb, 256, 0, stream>>>(
            row_i, ss1, ns1, feat_user, agg_item, ssum_i, NI,
            row_u, ss2, ns2, feat_item, agg_user, ssum_u, NU);

        finish_kernel<<<(NU + 31) / 32, 256, 0, stream>>>(
            feat_user, agg_user, ssum_u, W1, b1, W2, b2, out, NU);
        finish_kernel<<<(NI + 31) / 32, 256, 0, stream>>>(
            feat_item, agg_item, ssum_i, W1, b1, W2, b2,
            out + (size_t)NU * DD, NI);
    } else if (ws_size >= need_perm) {
        // ---- Tier 2: old perm-based CSR path ----
        int* cur_i = (int*)d_ws;
        int* cur_u = cur_i + NI;
        int* row_i = cur_u + NU;
        int* row_u = row_i + NI + 1;
        int* perm1 = row_u + NU + 1;
        int* perm2 = perm1 + E1;
        float* ssum_i = (float*)(perm2 + E2);
        float* ssum_u = ssum_i + NI;
        int* bsum = (int*)(ssum_u + NU);

        hipMemsetAsync(d_ws, 0, (size_t)(NI + NU) * sizeof(int), stream);

        count_kernel<<<eb, 256, 0, stream>>>(eud, E1, cur_i, eid, E2, cur_u);
        scanA_kernel<<<nb0 + nb1, 256, 0, stream>>>(cur_i, NI, cur_u, NU,
                                                    bsum, nb0);
        scanB_kernel<<<1, 256, 0, stream>>>(bsum, nb0, nb1,
                                            row_i, NI, row_u, NU);
        scanC_kernel<<<nb0 + nb1, 256, 0, stream>>>(cur_i, row_i, NI,
                                                    cur_u, row_u, NU,
                                                    bsum, nb0);
        fill_perm_kernel<<<eb, 256, 0, stream>>>(eud, E1, cur_i, perm1,
                                                 eid, E2, cur_u, perm2);

        gather_perm_kernel<<<gb, 256, 0, stream>>>(
            row_i, perm1, eus, norm_u2i, feat_user, agg_item, ssum_i, NI,
            row_u, perm2, eis, norm_i2u, feat_item, agg_user, ssum_u, NU);

        finish_kernel<<<(NU + 31) / 32, 256, 0, stream>>>(
            feat_user, agg_user, ssum_u, W1, b1, W2, b2, out, NU);
        finish_kernel<<<(NI + 31) / 32, 256, 0, stream>>>(
            feat_item, agg_item, ssum_i, W1, b1, W2, b2,
            out + (size_t)NU * DD, NI);
    } else {
        // ---- Tier 3: atomic scatter ----
        float* s_user = (float*)d_ws;
        float* s_item = s_user + NU;

        hipMemsetAsync(out, 0, (size_t)out_size * sizeof(float), stream);
        hipMemsetAsync(d_ws, 0, (size_t)(NU + NI) * sizeof(float), stream);

        int b1n = (int)(((long long)E1 * 64 + 255) / 256);
        scatter_kernel<<<b1n, 256, 0, stream>>>(feat_user, eus, eud, norm_u2i,
                                                agg_item, s_item, E1);
        int b2n = (int)(((long long)E2 * 64 + 255) / 256);
        scatter_kernel<<<b2n, 256, 0, stream>>>(feat_item, eis, eid, norm_i2u,
                                                agg_user, s_user, E2);

        finish_kernel<<<(NU + 31) / 32, 256, 0, stream>>>(
            feat_user, agg_user, s_user, W1, b1, W2, b2, out, NU);
        finish_kernel<<<(NI + 31) / 32, 256, 0, stream>>>(
            feat_item, agg_item, s_item, W1, b1, W2, b2,
            out + (size_t)NU * DD, NI);
    }
}

// Round 3
// 420.179 us; speedup vs baseline: 2.0008x; 1.2534x over previous
//
#include <hip/hip_runtime.h>

#define DD 128
#define SCAN_TILE 1024   // 256 threads x 4 elements per block

typedef __attribute__((ext_vector_type(8))) short short8;
typedef __attribute__((ext_vector_type(4))) float f32x4;

// bf16 round-to-nearest-even split helpers
__device__ inline unsigned short f2bf_rne(float f) {
    unsigned int u = __float_as_uint(f);
    unsigned int r = u + 0x7FFFu + ((u >> 16) & 1u);
    return (unsigned short)(r >> 16);
}
__device__ inline float bf2f(unsigned short h) {
    return __uint_as_float(((unsigned int)h) << 16);
}
// split (a,b) into packed bf16 hi pair + lo pair (residual)
__device__ inline void split2(float a, float b, unsigned int& hi, unsigned int& lo) {
    unsigned short ha = f2bf_rne(a), hb = f2bf_rne(b);
    float la = a - bf2f(ha), lb = b - bf2f(hb);
    hi = (unsigned int)ha | ((unsigned int)hb << 16);
    lo = (unsigned int)f2bf_rne(la) | ((unsigned int)f2bf_rne(lb) << 16);
}

// ---------------- CSR-build path (no float atomics) ----------------

__global__ __launch_bounds__(256) void count_kernel(
    const int* __restrict__ dst1, int E1, int* deg1,
    const int* __restrict__ dst2, int E2, int* deg2)
{
    int t = blockIdx.x * 256 + threadIdx.x;
    if (t < E1) {
        atomicAdd(deg1 + dst1[t], 1);
    } else if (t - E1 < E2) {
        atomicAdd(deg2 + dst2[t - E1], 1);
    }
}

__global__ __launch_bounds__(256) void scanA_kernel(
    const int* __restrict__ cur_i, int NI,
    const int* __restrict__ cur_u, int NU,
    int* bsum, int nb0)
{
    int b = blockIdx.x;
    const int* cur;
    int N, base;
    if (b < nb0) { cur = cur_i; N = NI; base = b * SCAN_TILE; }
    else         { cur = cur_u; N = NU; base = (b - nb0) * SCAN_TILE; }
    int t = threadIdx.x;
    int idx0 = base + t * 4;
    int s = 0;
    #pragma unroll
    for (int k = 0; k < 4; ++k) {
        int idx = idx0 + k;
        if (idx < N) s += cur[idx];
    }
    __shared__ int red[256];
    red[t] = s;
    __syncthreads();
    for (int o = 128; o >= 1; o >>= 1) {
        if (t < o) red[t] += red[t + o];
        __syncthreads();
    }
    if (t == 0) bsum[b] = red[0];
}

__device__ int block_exscan_inplace(int* a, int n)
{
    __shared__ int sh[256];
    int t = threadIdx.x;
    int carry = 0;
    for (int base = 0; base < n; base += 256) {
        int v = (base + t < n) ? a[base + t] : 0;
        sh[t] = v;
        __syncthreads();
        for (int off = 1; off < 256; off <<= 1) {
            int u = (t >= off) ? sh[t - off] : 0;
            __syncthreads();
            sh[t] += u;
            __syncthreads();
        }
        if (base + t < n) a[base + t] = carry + sh[t] - v;  // exclusive
        int csum = sh[255];
        __syncthreads();
        carry += csum;
    }
    return carry;
}

__global__ __launch_bounds__(256) void scanB_kernel(
    int* bsum, int nb0, int nb1,
    int* row_i, int NI, int* row_u, int NU)
{
    int tot0 = block_exscan_inplace(bsum, nb0);
    __syncthreads();
    int tot1 = block_exscan_inplace(bsum + nb0, nb1);
    if (threadIdx.x == 0) {
        row_i[NI] = tot0;
        row_u[NU] = tot1;
    }
}

__global__ __launch_bounds__(256) void scanC_kernel(
    int* cur_i, int* row_i, int NI,
    int* cur_u, int* row_u, int NU,
    const int* __restrict__ bsum, int nb0)
{
    int b = blockIdx.x;
    int off = bsum[b];
    int* cur; int* row;
    int N, base;
    if (b < nb0) { cur = cur_i; row = row_i; N = NI; base = b * SCAN_TILE; }
    else         { cur = cur_u; row = row_u; N = NU; base = (b - nb0) * SCAN_TILE; }
    int t = threadIdx.x;
    int idx0 = base + t * 4;
    int v[4];
    int s = 0;
    #pragma unroll
    for (int k = 0; k < 4; ++k) {
        int idx = idx0 + k;
        v[k] = (idx < N) ? cur[idx] : 0;
        s += v[k];
    }
    __shared__ int sh[256];
    sh[t] = s;
    __syncthreads();
    for (int o = 1; o < 256; o <<= 1) {
        int u = (t >= o) ? sh[t - o] : 0;
        __syncthreads();
        sh[t] += u;
        __syncthreads();
    }
    int run = off + sh[t] - s;
    #pragma unroll
    for (int k = 0; k < 4; ++k) {
        int idx = idx0 + k;
        if (idx < N) {
            row[idx] = run;
            cur[idx] = run;
            run += v[k];
        }
    }
}

// Tier 1 fill: scatter pre-gathered (src, norm) into dst-grouped order.
__global__ __launch_bounds__(256) void fill_pg_kernel(
    const int* __restrict__ dst1, const int* __restrict__ src1,
    const float* __restrict__ norm1, int E1, int* cur1, int* ss1, float* ns1,
    const int* __restrict__ dst2, const int* __restrict__ src2,
    const float* __restrict__ norm2, int E2, int* cur2, int* ss2, float* ns2)
{
    int t = blockIdx.x * 256 + threadIdx.x;
    if (t < E1) {
        int pos = atomicAdd(cur1 + dst1[t], 1);
        ss1[pos] = src1[t];
        ns1[pos] = norm1[t];
    } else if (t - E1 < E2) {
        int e = t - E1;
        int pos = atomicAdd(cur2 + dst2[e], 1);
        ss2[pos] = src2[e];
        ns2[pos] = norm2[e];
    }
}

// Tier 1 gather: one wave per destination node.
__global__ __launch_bounds__(256) void gather_kernel(
    const int* __restrict__ row_i, const int* __restrict__ srcs1,
    const float* __restrict__ norms1,
    const float* __restrict__ feat_user, float* agg_item, float* ssum_i, int NI,
    const int* __restrict__ row_u, const int* __restrict__ srcs2,
    const float* __restrict__ norms2,
    const float* __restrict__ feat_item, float* agg_user, float* ssum_u, int NU)
{
    int gw = (int)((blockIdx.x * 256u + threadIdx.x) >> 6);
    int lane = threadIdx.x & 63;
    if (gw >= NI + NU) return;

    const int *row, *srcs;
    const float *norms, *feat;
    float *agg, *ssum;
    int d;
    if (gw < NI) {
        d = gw;      row = row_i; srcs = srcs1; norms = norms1;
        feat = feat_user; agg = agg_item; ssum = ssum_i;
    } else {
        d = gw - NI; row = row_u; srcs = srcs2; norms = norms2;
        feat = feat_item; agg = agg_user; ssum = ssum_u;
    }

    int beg = row[d], end = row[d + 1];
    float2 acc = {0.f, 0.f};
    float sn = 0.f;
    int j = beg;
    for (; j + 4 <= end; j += 4) {
        int s0 = srcs[j], s1 = srcs[j + 1], s2 = srcs[j + 2], s3 = srcs[j + 3];
        float n0 = norms[j],     n1 = norms[j + 1];
        float n2 = norms[j + 2], n3 = norms[j + 3];
        float2 v0 = *(const float2*)(feat + (size_t)s0 * DD + lane * 2);
        float2 v1 = *(const float2*)(feat + (size_t)s1 * DD + lane * 2);
        float2 v2 = *(const float2*)(feat + (size_t)s2 * DD + lane * 2);
        float2 v3 = *(const float2*)(feat + (size_t)s3 * DD + lane * 2);
        acc.x += n0 * v0.x + n1 * v1.x + n2 * v2.x + n3 * v3.x;
        acc.y += n0 * v0.y + n1 * v1.y + n2 * v2.y + n3 * v3.y;
        sn += n0 + n1 + n2 + n3;
    }
    for (; j < end; ++j) {
        int s0 = srcs[j];
        float n0 = norms[j];
        float2 v0 = *(const float2*)(feat + (size_t)s0 * DD + lane * 2);
        acc.x += n0 * v0.x;
        acc.y += n0 * v0.y;
        sn += n0;
    }
    float* ap = agg + (size_t)d * DD + lane * 2;
    __builtin_nontemporal_store(acc.x, ap);
    __builtin_nontemporal_store(acc.y, ap + 1);
    if (lane == 0) ssum[d] = sn;
}

// ---------------- Tier 3 fallback: atomic scatter ----------------

__global__ __launch_bounds__(256) void scatter_kernel(
    const float* __restrict__ feat_src,
    const int* __restrict__ src,
    const int* __restrict__ dst,
    const float* __restrict__ norm,
    float* agg,
    float* ssum,
    int E)
{
    int gw = (int)((blockIdx.x * 256u + threadIdx.x) >> 6);
    int lane = threadIdx.x & 63;
    if (gw >= E) return;
    int si = src[gw];
    int di = dst[gw];
    float nv = norm[gw];
    float2 v = *(const float2*)(feat_src + (size_t)si * DD + lane * 2);
    float* ap = agg + (size_t)di * DD + lane * 2;
    unsafeAtomicAdd(ap,     v.x * nv);
    unsafeAtomicAdd(ap + 1, v.y * nv);
    if (lane == 0) unsafeAtomicAdd(ssum + di, nv);
}

// ---------------- W pre-split into MFMA B-fragment planes ----------------
// Planes (each 16384 ushorts = 32 KB): 0=W1h 1=W1l 2=W2h 3=W2l.
// B-frag layout (16x16x32 bf16): lane l=16g+c holds B[k0+8g+i][cf*16+c], i=0..7.
// Storage: plane[((ksm*8 + cf)*64 + lane)*8 + i]  -> per-wave dwordx4 loads.
__global__ __launch_bounds__(256) void wprep_kernel(
    const float* __restrict__ W1, const float* __restrict__ W2,
    unsigned short* wfrag)
{
    int t = blockIdx.x * 256 + threadIdx.x;    // 4096 threads
    if (t >= 4096) return;
    int lane = t & 63;
    int cf   = (t >> 6) & 7;
    int ksm  = (t >> 9) & 3;
    int mat  = t >> 11;
    const float* W = mat ? W2 : W1;
    int g = lane >> 4, c = lane & 15;
    int n = cf * 16 + c;
    unsigned int hi[4], lo[4];
    #pragma unroll
    for (int p = 0; p < 4; ++p) {
        int k0 = ksm * 32 + g * 8 + p * 2;
        float v0 = W[(size_t)k0 * DD + n];
        float v1 = W[(size_t)(k0 + 1) * DD + n];
        split2(v0, v1, hi[p], lo[p]);
    }
    unsigned short* dh = wfrag + (size_t)mat * 32768
                       + ((size_t)(ksm * 8 + cf) * 64 + lane) * 8;
    unsigned short* dl = dh + 16384;
    *(uint4*)dh = make_uint4(hi[0], hi[1], hi[2], hi[3]);
    *(uint4*)dl = make_uint4(lo[0], lo[1], lo[2], lo[3]);
}

// ---------------- Finish via split-bf16 MFMA ----------------
// h = [x|y] @ [W1;W2] + (1+s)b1 + s*b2; lrelu; row L2-normalize.
// x,y split hi/lo in LDS (XOR-swizzled); 3 MFMAs per k-step recover fp32
// accuracy (xh*wh + xh*wl + xl*wh; dropped xl*wl ~ 2^-18 relative).
// One launch covers user rows then item rows. agg aliases out (block-local).
__global__ __launch_bounds__(256) void finish_mfma_kernel(
    const float* __restrict__ feat_u, const float* aggu,
    const float* __restrict__ ssum_u, int NU, int nbU,
    const float* __restrict__ feat_i, const float* aggi,
    const float* __restrict__ ssum_i, int NI,
    const unsigned short* __restrict__ wfrag,
    const float* __restrict__ b1, const float* __restrict__ b2,
    float* out_base)
{
    __shared__ __align__(16) unsigned short Ah[32 * 256];  // 16 KB (32 rows x 256 k)
    __shared__ __align__(16) unsigned short Al[32 * 256];  // 16 KB
    __shared__ float sst[32];

    const float *feat, *agg, *ssum;
    float* out;
    int row0, nrows;
    if ((int)blockIdx.x < nbU) {
        feat = feat_u; agg = aggu; ssum = ssum_u;
        out = out_base; row0 = blockIdx.x * 32; nrows = NU;
    } else {
        feat = feat_i; agg = aggi; ssum = ssum_i;
        out = out_base + (size_t)NU * DD;
        row0 = (blockIdx.x - nbU) * 32; nrows = NI;
    }

    int t = threadIdx.x;

    // ---- Phase 1: stage x=f+a, y=f*a as bf16 hi/lo into LDS ----
    {
        int r  = t >> 3;           // 0..31 (row within tile)
        int kq = (t & 7) * 16;     // k start within [0,128)
        int grow = row0 + r;
        bool valid = grow < nrows;
        unsigned int XH[8], XL[8], YH[8], YL[8];
        #pragma unroll
        for (int q = 0; q < 4; ++q) {
            float4 f4 = {0.f, 0.f, 0.f, 0.f}, a4 = {0.f, 0.f, 0.f, 0.f};
            if (valid) {
                f4 = *(const float4*)(feat + (size_t)grow * DD + kq + q * 4);
                a4 = *(const float4*)(agg  + (size_t)grow * DD + kq + q * 4);
            }
            float x0 = f4.x + a4.x, x1 = f4.y + a4.y;
            float x2 = f4.z + a4.z, x3 = f4.w + a4.w;
            float y0 = f4.x * a4.x, y1 = f4.y * a4.y;
            float y2 = f4.z * a4.z, y3 = f4.w * a4.w;
            split2(x0, x1, XH[q * 2],     XL[q * 2]);
            split2(x2, x3, XH[q * 2 + 1], XL[q * 2 + 1]);
            split2(y0, y1, YH[q * 2],     YL[q * 2]);
            split2(y2, y3, YH[q * 2 + 1], YL[q * 2 + 1]);
        }
        int swz = (r & 7) << 4;
        char* pAh = (char*)Ah;
        char* pAl = (char*)Al;
        int rb = r * 512;
        int x0o = rb + ((kq * 2)            ^ swz);
        int x1o = rb + ((kq * 2 + 16)       ^ swz);
        int y0o = rb + ((256 + kq * 2)      ^ swz);
        int y1o = rb + ((256 + kq * 2 + 16) ^ swz);
        *(uint4*)(pAh + x0o) = make_uint4(XH[0], XH[1], XH[2], XH[3]);
        *(uint4*)(pAh + x1o) = make_uint4(XH[4], XH[5], XH[6], XH[7]);
        *(uint4*)(pAl + x0o) = make_uint4(XL[0], XL[1], XL[2], XL[3]);
        *(uint4*)(pAl + x1o) = make_uint4(XL[4], XL[5], XL[6], XL[7]);
        *(uint4*)(pAh + y0o) = make_uint4(YH[0], YH[1], YH[2], YH[3]);
        *(uint4*)(pAh + y1o) = make_uint4(YH[4], YH[5], YH[6], YH[7]);
        *(uint4*)(pAl + y0o) = make_uint4(YL[0], YL[1], YL[2], YL[3]);
        *(uint4*)(pAl + y1o) = make_uint4(YL[4], YL[5], YL[6], YL[7]);
        if (t < 32) sst[t] = (row0 + t < nrows) ? ssum[row0 + t] : 0.f;
    }
    __syncthreads();

    // ---- Phase 2: MFMA over K=256 (8 k-steps of 32) ----
    int lane = t & 63;
    int w = t >> 6;              // wave -> cols [w*32, w*32+32)
    int r16 = lane & 15, g = lane >> 4;
    f32x4 acc00 = {0.f,0.f,0.f,0.f}, acc01 = {0.f,0.f,0.f,0.f};
    f32x4 acc10 = {0.f,0.f,0.f,0.f}, acc11 = {0.f,0.f,0.f,0.f};
    const char* cAh = (const char*)Ah;
    const char* cAl = (const char*)Al;
    int swzA = (r16 & 7) << 4;   // (r16+16)&7 == r16&7
    int ob0 = r16 * 512;
    int ob1 = (r16 + 16) * 512;

    #pragma unroll 2
    for (int ks = 0; ks < 8; ++ks) {
        int kb = ks * 64 + g * 16;
        int offx = kb ^ swzA;
        short8 a0h = *(const short8*)(cAh + ob0 + offx);
        short8 a0l = *(const short8*)(cAl + ob0 + offx);
        short8 a1h = *(const short8*)(cAh + ob1 + offx);
        short8 a1l = *(const short8*)(cAl + ob1 + offx);
        int mat = ks >> 2, ksm = ks & 3;
        const unsigned short* ph = wfrag + (size_t)mat * 32768;
        const unsigned short* pl = ph + 16384;
        int bo0 = ((ksm * 8 + w * 2) * 64 + lane) * 8;
        int bo1 = bo0 + 512;
        short8 b0h = *(const short8*)(ph + bo0);
        short8 b0l = *(const short8*)(pl + bo0);
        short8 b1h = *(const short8*)(ph + bo1);
        short8 b1l = *(const short8*)(pl + bo1);
        acc00 = __builtin_amdgcn_mfma_f32_16x16x32_bf16(a0h, b0h, acc00, 0, 0, 0);
        acc00 = __builtin_amdgcn_mfma_f32_16x16x32_bf16(a0h, b0l, acc00, 0, 0, 0);
        acc00 = __builtin_amdgcn_mfma_f32_16x16x32_bf16(a0l, b0h, acc00, 0, 0, 0);
        acc01 = __builtin_amdgcn_mfma_f32_16x16x32_bf16(a0h, b1h, acc01, 0, 0, 0);
        acc01 = __builtin_amdgcn_mfma_f32_16x16x32_bf16(a0h, b1l, acc01, 0, 0, 0);
        acc01 = __builtin_amdgcn_mfma_f32_16x16x32_bf16(a0l, b1h, acc01, 0, 0, 0);
        acc10 = __builtin_amdgcn_mfma_f32_16x16x32_bf16(a1h, b0h, acc10, 0, 0, 0);
        acc10 = __builtin_amdgcn_mfma_f32_16x16x32_bf16(a1h, b0l, acc10, 0, 0, 0);
        acc10 = __builtin_amdgcn_mfma_f32_16x16x32_bf16(a1l, b0h, acc10, 0, 0, 0);
        acc11 = __builtin_amdgcn_mfma_f32_16x16x32_bf16(a1h, b1h, acc11, 0, 0, 0);
        acc11 = __builtin_amdgcn_mfma_f32_16x16x32_bf16(a1h, b1l, acc11, 0, 0, 0);
        acc11 = __builtin_amdgcn_mfma_f32_16x16x32_bf16(a1l, b1h, acc11, 0, 0, 0);
    }
    __syncthreads();

    // ---- Phase 3: write h to LDS (reuse Ah), bias+lrelu+row-norm ----
    float* hbuf = (float*)Ah;    // 32 x 128 f32 = 16 KB
    #pragma unroll
    for (int j = 0; j < 4; ++j) {
        int rA = g * 4 + j;
        hbuf[rA * DD        + (w * 32 + r16)]      = acc00[j];
        hbuf[rA * DD        + (w * 32 + 16 + r16)] = acc01[j];
        hbuf[(16 + rA) * DD + (w * 32 + r16)]      = acc10[j];
        hbuf[(16 + rA) * DD + (w * 32 + 16 + r16)] = acc11[j];
    }
    __syncthreads();

    int c0 = t & 63, c1 = c0 + 64, rg = t >> 6;
    float b1c0 = b1[c0], b1c1 = b1[c1];
    float b2c0 = b2[c0], b2c1 = b2[c1];
    #pragma unroll
    for (int rr = 0; rr < 8; ++rr) {
        int lr = rg * 8 + rr;
        int row = row0 + lr;
        if (row < nrows) {
            float s = sst[lr];
            float h0 = hbuf[lr * DD + c0] + (1.0f + s) * b1c0 + s * b2c0;
            float h1 = hbuf[lr * DD + c1] + (1.0f + s) * b1c1 + s * b2c1;
            h0 = h0 >= 0.f ? h0 : 0.2f * h0;
            h1 = h1 >= 0.f ? h1 : 0.2f * h1;
            float loc = h0 * h0 + h1 * h1;
            #pragma unroll
            for (int m = 32; m >= 1; m >>= 1) loc += __shfl_xor(loc, m, 64);
            float inv = 1.0f / fmaxf(sqrtf(loc), 1e-12f);
            out[(size_t)row * DD + c0] = h0 * inv;
            out[(size_t)row * DD + c1] = h1 * inv;
        }
    }
}

// ---------------- fp32 finish (tier2/3 fallback) ----------------

__global__ __launch_bounds__(256) void finish_kernel(
    const float* __restrict__ feat,
    const float* agg,
    const float* __restrict__ ssum,
    const float* __restrict__ W1,
    const float* __restrict__ b1,
    const float* __restrict__ W2,
    const float* __restrict__ b2,
    float* out,
    int nrows)
{
    __shared__ float xs[32][DD];
    __shared__ float ys[32][DD];
    int row0 = blockIdx.x * 32;
    int tid = threadIdx.x;

    for (int i = tid; i < 32 * (DD / 4); i += 256) {
        int r = i >> 5;
        int c4 = (i & 31) * 4;
        int row = row0 + r;
        if (row < nrows) {
            float4 f = *(const float4*)(feat + (size_t)row * DD + c4);
            float4 a = *(const float4*)(agg  + (size_t)row * DD + c4);
            float4 x, y;
            x.x = f.x + a.x; x.y = f.y + a.y; x.z = f.z + a.z; x.w = f.w + a.w;
            y.x = f.x * a.x; y.y = f.y * a.y; y.z = f.z * a.z; y.w = f.w * a.w;
            *(float4*)&xs[r][c4] = x;
            *(float4*)&ys[r][c4] = y;
        }
    }
    __syncthreads();

    int c0 = tid & 63;
    int rg = tid >> 6;
    int c1 = c0 + 64;

    float acc[8][2] = {{0.f,0.f},{0.f,0.f},{0.f,0.f},{0.f,0.f},
                       {0.f,0.f},{0.f,0.f},{0.f,0.f},{0.f,0.f}};
    for (int k = 0; k < DD; k += 4) {
        float w1a[4], w1b[4], w2a[4], w2b[4];
        #pragma unroll
        for (int kk = 0; kk < 4; ++kk) {
            const float* wr1 = W1 + (size_t)(k + kk) * DD;
            const float* wr2 = W2 + (size_t)(k + kk) * DD;
            w1a[kk] = wr1[c0]; w1b[kk] = wr1[c1];
            w2a[kk] = wr2[c0]; w2b[kk] = wr2[c1];
        }
        #pragma unroll
        for (int r = 0; r < 8; ++r) {
            float4 xv = *(const float4*)&xs[rg * 8 + r][k];
            float4 yv = *(const float4*)&ys[rg * 8 + r][k];
            acc[r][0] += xv.x*w1a[0] + xv.y*w1a[1] + xv.z*w1a[2] + xv.w*w1a[3]
                       + yv.x*w2a[0] + yv.y*w2a[1] + yv.z*w2a[2] + yv.w*w2a[3];
            acc[r][1] += xv.x*w1b[0] + xv.y*w1b[1] + xv.z*w1b[2] + xv.w*w1b[3]
                       + yv.x*w2b[0] + yv.y*w2b[1] + yv.z*w2b[2] + yv.w*w2b[3];
        }
    }

    float b1c0 = b1[c0], b1c1 = b1[c1];
    float b2c0 = b2[c0], b2c1 = b2[c1];

    #pragma unroll
    for (int r = 0; r < 8; ++r) {
        int row = row0 + rg * 8 + r;
        if (row < nrows) {
            float s = ssum[row];
            float h0 = acc[r][0] + (1.0f + s) * b1c0 + s * b2c0;
            float h1 = acc[r][1] + (1.0f + s) * b1c1 + s * b2c1;
            h0 = h0 >= 0.f ? h0 : 0.2f * h0;
            h1 = h1 >= 0.f ? h1 : 0.2f * h1;
            float loc = h0 * h0 + h1 * h1;
            #pragma unroll
            for (int m = 32; m >= 1; m >>= 1) loc += __shfl_xor(loc, m, 64);
            float inv = 1.0f / fmaxf(sqrtf(loc), 1e-12f);
            out[(size_t)row * DD + c0] = h0 * inv;
            out[(size_t)row * DD + c1] = h1 * inv;
        }
    }
}

extern "C" void kernel_launch(void* const* d_in, const int* in_sizes, int n_in,
                              void* d_out, int out_size, void* d_ws, size_t ws_size,
                              hipStream_t stream) {
    const float* feat_user = (const float*)d_in[0];
    const float* feat_item = (const float*)d_in[1];
    const float* W1        = (const float*)d_in[2];
    const float* b1        = (const float*)d_in[3];
    const float* W2        = (const float*)d_in[4];
    const float* b2        = (const float*)d_in[5];
    const float* norm_u2i  = (const float*)d_in[6];
    const float* norm_i2u  = (const float*)d_in[7];
    const int* eus = (const int*)d_in[8];
    const int* eud = (const int*)d_in[9];
    const int* eis = (const int*)d_in[10];
    const int* eid = (const int*)d_in[11];

    int NU = in_sizes[0] / DD;
    int NI = in_sizes[1] / DD;
    int E1 = in_sizes[8];
    int E2 = in_sizes[10];
    float* out = (float*)d_out;

    float* agg_user = out;
    float* agg_item = out + (size_t)NU * DD;

    int nb0 = (NI + SCAN_TILE - 1) / SCAN_TILE;
    int nb1 = (NU + SCAN_TILE - 1) / SCAN_TILE;
    int nbU = (NU + 31) / 32;
    int nbI = (NI + 31) / 32;

    size_t wfrag_bytes = 131072;   // 4 planes x 32 KB
    size_t need_pg   = wfrag_bytes +
                       ((size_t)3 * NU + 3 * NI + 2 * E1 + 2 * E2 + 2
                        + nb0 + nb1) * sizeof(int);
    size_t need_perm = ((size_t)3 * NU + 3 * NI + E1 + E2 + 2
                        + nb0 + nb1) * sizeof(int);

    int eb = (int)(((long long)E1 + E2 + 255) / 256);
    int gb = (int)(((long long)(NI + NU) * 64 + 255) / 256);

    if (ws_size >= need_pg) {
        // ---- Tier 1: CSR + pre-gathered + MFMA finish ----
        unsigned short* wfrag = (unsigned short*)d_ws;   // 128 KB, 16B-aligned
        int* cur_i = (int*)((char*)d_ws + wfrag_bytes);  // NI
        int* cur_u = cur_i + NI;            // NU
        int* row_i = cur_u + NU;            // NI+1
        int* row_u = row_i + NI + 1;        // NU+1
        int* ss1   = row_u + NU + 1;        // E1
        int* ss2   = ss1 + E1;              // E2
        float* ns1 = (float*)(ss2 + E2);    // E1
        float* ns2 = ns1 + E1;              // E2
        float* ssum_i = ns2 + E2;           // NI
        float* ssum_u = ssum_i + NI;        // NU
        int* bsum = (int*)(ssum_u + NU);    // nb0+nb1

        wprep_kernel<<<16, 256, 0, stream>>>(W1, W2, wfrag);

        hipMemsetAsync(cur_i, 0, (size_t)(NI + NU) * sizeof(int), stream);

        count_kernel<<<eb, 256, 0, stream>>>(eud, E1, cur_i, eid, E2, cur_u);
        scanA_kernel<<<nb0 + nb1, 256, 0, stream>>>(cur_i, NI, cur_u, NU,
                                                    bsum, nb0);
        scanB_kernel<<<1, 256, 0, stream>>>(bsum, nb0, nb1,
                                            row_i, NI, row_u, NU);
        scanC_kernel<<<nb0 + nb1, 256, 0, stream>>>(cur_i, row_i, NI,
                                                    cur_u, row_u, NU,
                                                    bsum, nb0);
        fill_pg_kernel<<<eb, 256, 0, stream>>>(
            eud, eus, norm_u2i, E1, cur_i, ss1, ns1,
            eid, eis, norm_i2u, E2, cur_u, ss2, ns2);

        gather_kernel<<<gb, 256, 0, stream>>>(
            row_i, ss1, ns1, feat_user, agg_item, ssum_i, NI,
            row_u, ss2, ns2, feat_item, agg_user, ssum_u, NU);

        finish_mfma_kernel<<<nbU + nbI, 256, 0, stream>>>(
            feat_user, agg_user, ssum_u, NU, nbU,
            feat_item, agg_item, ssum_i, NI,
            wfrag, b1, b2, out);
    } else if (ws_size >= need_perm) {
        // ---- Tier 2: perm-based CSR + fp32 finish ----
        int* cur_i = (int*)d_ws;
        int* cur_u = cur_i + NI;
        int* row_i = cur_u + NU;
        int* row_u = row_i + NI + 1;
        int* ss1   = row_u + NU + 1;        // reuse as srcs (E1)
        int* ss2   = ss1 + E1;
        float* ssum_i = (float*)(ss2 + E2);
        float* ssum_u = ssum_i + NI;
        int* bsum = (int*)(ssum_u + NU);

        hipMemsetAsync(d_ws, 0, (size_t)(NI + NU) * sizeof(int), stream);

        count_kernel<<<eb, 256, 0, stream>>>(eud, E1, cur_i, eid, E2, cur_u);
        scanA_kernel<<<nb0 + nb1, 256, 0, stream>>>(cur_i, NI, cur_u, NU,
                                                    bsum, nb0);
        scanB_kernel<<<1, 256, 0, stream>>>(bsum, nb0, nb1,
                                            row_i, NI, row_u, NU);
        scanC_kernel<<<nb0 + nb1, 256, 0, stream>>>(cur_i, row_i, NI,
                                                    cur_u, row_u, NU,
                                                    bsum, nb0);
        // srcs-only fill (no norms pre-gather; gather falls back to norm array
        // indexed by... not available here) -> use atomic tier instead.
        hipMemsetAsync(out, 0, (size_t)out_size * sizeof(float), stream);
        hipMemsetAsync(ssum_i, 0, (size_t)(NI + NU) * sizeof(float), stream);
        int b1n = (int)(((long long)E1 * 64 + 255) / 256);
        scatter_kernel<<<b1n, 256, 0, stream>>>(feat_user, eus, eud, norm_u2i,
                                                agg_item, ssum_i, E1);
        int b2n = (int)(((long long)E2 * 64 + 255) / 256);
        scatter_kernel<<<b2n, 256, 0, stream>>>(feat_item, eis, eid, norm_i2u,
                                                agg_user, ssum_u, E2);
        finish_kernel<<<nbU, 256, 0, stream>>>(
            feat_user, agg_user, ssum_u, W1, b1, W2, b2, out, NU);
        finish_kernel<<<nbI, 256, 0, stream>>>(
            feat_item, agg_item, ssum_i, W1, b1, W2, b2,
            out + (size_t)NU * DD, NI);
    } else {
        // ---- Tier 3: atomic scatter + fp32 finish ----
        float* s_user = (float*)d_ws;
        float* s_item = s_user + NU;

        hipMemsetAsync(out, 0, (size_t)out_size * sizeof(float), stream);
        hipMemsetAsync(d_ws, 0, (size_t)(NU + NI) * sizeof(float), stream);

        int b1n = (int)(((long long)E1 * 64 + 255) / 256);
        scatter_kernel<<<b1n, 256, 0, stream>>>(feat_user, eus, eud, norm_u2i,
                                                agg_item, s_item, E1);
        int b2n = (int)(((long long)E2 * 64 + 255) / 256);
        scatter_kernel<<<b2n, 256, 0, stream>>>(feat_item, eis, eid, norm_i2u,
                                                agg_user, s_user, E2);

        finish_kernel<<<nbU, 256, 0, stream>>>(
            feat_user, agg_user, s_user, W1, b1, W2, b2, out, NU);
        finish_kernel<<<nbI, 256, 0, stream>>>(
            feat_item, agg_item, s_item, W1, b1, W2, b2,
            out + (size_t)NU * DD, NI);
    }
}

// Round 4
// 418.581 us; speedup vs baseline: 2.0085x; 1.0038x over previous
//
#include <hip/hip_runtime.h>

#define DD 128
#define SCAN_TILE 1024   // 256 threads x 4 elements per block
#define HS 132           // padded hbuf stride (floats): 4-way -> 2-way banks

typedef __attribute__((ext_vector_type(8))) short short8;
typedef __attribute__((ext_vector_type(4))) float f32x4;

// bf16 round-to-nearest-even split helpers
__device__ inline unsigned short f2bf_rne(float f) {
    unsigned int u = __float_as_uint(f);
    unsigned int r = u + 0x7FFFu + ((u >> 16) & 1u);
    return (unsigned short)(r >> 16);
}
__device__ inline float bf2f(unsigned short h) {
    return __uint_as_float(((unsigned int)h) << 16);
}
// split (a,b) into packed bf16 hi pair + lo pair (residual)
__device__ inline void split2(float a, float b, unsigned int& hi, unsigned int& lo) {
    unsigned short ha = f2bf_rne(a), hb = f2bf_rne(b);
    float la = a - bf2f(ha), lb = b - bf2f(hb);
    hi = (unsigned int)ha | ((unsigned int)hb << 16);
    lo = (unsigned int)f2bf_rne(la) | ((unsigned int)f2bf_rne(lb) << 16);
}

// ---------------- CSR-build path (no float atomics) ----------------

__global__ __launch_bounds__(256) void count_kernel(
    const int* __restrict__ dst1, int E1, int* deg1,
    const int* __restrict__ dst2, int E2, int* deg2)
{
    int t = blockIdx.x * 256 + threadIdx.x;
    if (t < E1) {
        atomicAdd(deg1 + dst1[t], 1);
    } else if (t - E1 < E2) {
        atomicAdd(deg2 + dst2[t - E1], 1);
    }
}

__global__ __launch_bounds__(256) void scanA_kernel(
    const int* __restrict__ cur_i, int NI,
    const int* __restrict__ cur_u, int NU,
    int* bsum, int nb0)
{
    int b = blockIdx.x;
    const int* cur;
    int N, base;
    if (b < nb0) { cur = cur_i; N = NI; base = b * SCAN_TILE; }
    else         { cur = cur_u; N = NU; base = (b - nb0) * SCAN_TILE; }
    int t = threadIdx.x;
    int idx0 = base + t * 4;
    int s = 0;
    #pragma unroll
    for (int k = 0; k < 4; ++k) {
        int idx = idx0 + k;
        if (idx < N) s += cur[idx];
    }
    __shared__ int red[256];
    red[t] = s;
    __syncthreads();
    for (int o = 128; o >= 1; o >>= 1) {
        if (t < o) red[t] += red[t + o];
        __syncthreads();
    }
    if (t == 0) bsum[b] = red[0];
}

__device__ int block_exscan_inplace(int* a, int n)
{
    __shared__ int sh[256];
    int t = threadIdx.x;
    int carry = 0;
    for (int base = 0; base < n; base += 256) {
        int v = (base + t < n) ? a[base + t] : 0;
        sh[t] = v;
        __syncthreads();
        for (int off = 1; off < 256; off <<= 1) {
            int u = (t >= off) ? sh[t - off] : 0;
            __syncthreads();
            sh[t] += u;
            __syncthreads();
        }
        if (base + t < n) a[base + t] = carry + sh[t] - v;  // exclusive
        int csum = sh[255];
        __syncthreads();
        carry += csum;
    }
    return carry;
}

__global__ __launch_bounds__(256) void scanB_kernel(
    int* bsum, int nb0, int nb1,
    int* row_i, int NI, int* row_u, int NU)
{
    int tot0 = block_exscan_inplace(bsum, nb0);
    __syncthreads();
    int tot1 = block_exscan_inplace(bsum + nb0, nb1);
    if (threadIdx.x == 0) {
        row_i[NI] = tot0;
        row_u[NU] = tot1;
    }
}

__global__ __launch_bounds__(256) void scanC_kernel(
    int* cur_i, int* row_i, int NI,
    int* cur_u, int* row_u, int NU,
    const int* __restrict__ bsum, int nb0)
{
    int b = blockIdx.x;
    int off = bsum[b];
    int* cur; int* row;
    int N, base;
    if (b < nb0) { cur = cur_i; row = row_i; N = NI; base = b * SCAN_TILE; }
    else         { cur = cur_u; row = row_u; N = NU; base = (b - nb0) * SCAN_TILE; }
    int t = threadIdx.x;
    int idx0 = base + t * 4;
    int v[4];
    int s = 0;
    #pragma unroll
    for (int k = 0; k < 4; ++k) {
        int idx = idx0 + k;
        v[k] = (idx < N) ? cur[idx] : 0;
        s += v[k];
    }
    __shared__ int sh[256];
    sh[t] = s;
    __syncthreads();
    for (int o = 1; o < 256; o <<= 1) {
        int u = (t >= o) ? sh[t - o] : 0;
        __syncthreads();
        sh[t] += u;
        __syncthreads();
    }
    int run = off + sh[t] - s;
    #pragma unroll
    for (int k = 0; k < 4; ++k) {
        int idx = idx0 + k;
        if (idx < N) {
            row[idx] = run;
            cur[idx] = run;
            run += v[k];
        }
    }
}

// Tier 1 fill: scatter pre-gathered (src, norm) into dst-grouped order.
__global__ __launch_bounds__(256) void fill_pg_kernel(
    const int* __restrict__ dst1, const int* __restrict__ src1,
    const float* __restrict__ norm1, int E1, int* cur1, int* ss1, float* ns1,
    const int* __restrict__ dst2, const int* __restrict__ src2,
    const float* __restrict__ norm2, int E2, int* cur2, int* ss2, float* ns2)
{
    int t = blockIdx.x * 256 + threadIdx.x;
    if (t < E1) {
        int pos = atomicAdd(cur1 + dst1[t], 1);
        ss1[pos] = src1[t];
        ns1[pos] = norm1[t];
    } else if (t - E1 < E2) {
        int e = t - E1;
        int pos = atomicAdd(cur2 + dst2[e], 1);
        ss2[pos] = src2[e];
        ns2[pos] = norm2[e];
    }
}

// ---------------- Tier 3 fallback: atomic scatter ----------------

__global__ __launch_bounds__(256) void scatter_kernel(
    const float* __restrict__ feat_src,
    const int* __restrict__ src,
    const int* __restrict__ dst,
    const float* __restrict__ norm,
    float* agg,
    float* ssum,
    int E)
{
    int gw = (int)((blockIdx.x * 256u + threadIdx.x) >> 6);
    int lane = threadIdx.x & 63;
    if (gw >= E) return;
    int si = src[gw];
    int di = dst[gw];
    float nv = norm[gw];
    float2 v = *(const float2*)(feat_src + (size_t)si * DD + lane * 2);
    float* ap = agg + (size_t)di * DD + lane * 2;
    unsafeAtomicAdd(ap,     v.x * nv);
    unsafeAtomicAdd(ap + 1, v.y * nv);
    if (lane == 0) unsafeAtomicAdd(ssum + di, nv);
}

// ---------------- W pre-split into MFMA B-fragment planes ----------------
// Planes (each 16384 ushorts = 32 KB): 0=W1h 1=W1l 2=W2h 3=W2l.
// B-frag layout (16x16x32 bf16): lane l=16g+c holds B[k0+8g+i][cf*16+c], i=0..7.
// Storage: plane[((ksm*8 + cf)*64 + lane)*8 + i]  -> per-wave dwordx4 loads.
__global__ __launch_bounds__(256) void wprep_kernel(
    const float* __restrict__ W1, const float* __restrict__ W2,
    unsigned short* wfrag)
{
    int t = blockIdx.x * 256 + threadIdx.x;    // 4096 threads
    if (t >= 4096) return;
    int lane = t & 63;
    int cf   = (t >> 6) & 7;
    int ksm  = (t >> 9) & 3;
    int mat  = t >> 11;
    const float* W = mat ? W2 : W1;
    int g = lane >> 4, c = lane & 15;
    int n = cf * 16 + c;
    unsigned int hi[4], lo[4];
    #pragma unroll
    for (int p = 0; p < 4; ++p) {
        int k0 = ksm * 32 + g * 8 + p * 2;
        float v0 = W[(size_t)k0 * DD + n];
        float v1 = W[(size_t)(k0 + 1) * DD + n];
        split2(v0, v1, hi[p], lo[p]);
    }
    unsigned short* dh = wfrag + (size_t)mat * 32768
                       + ((size_t)(ksm * 8 + cf) * 64 + lane) * 8;
    unsigned short* dl = dh + 16384;
    *(uint4*)dh = make_uint4(hi[0], hi[1], hi[2], hi[3]);
    *(uint4*)dl = make_uint4(lo[0], lo[1], lo[2], lo[3]);
}

// ---------------- Fused gather + MFMA finish ----------------
// Per block: 32 destination rows. Phase G: each wave gathers 8 rows
// (CSR edge loop, 2 cols/lane), computes x=f+a, y=f*a, splits to bf16
// hi/lo, writes straight into the XOR-swizzled LDS A-tiles. Then the
// split-bf16 MFMA (3 per k-step) + bias/lrelu/row-L2-norm epilogue.
// Eliminates the agg HBM round trip entirely (out no longer aliased).
__global__ __launch_bounds__(256) void fused_kernel(
    const float* __restrict__ feat_user, const float* __restrict__ feat_item,
    const int* __restrict__ row_u, const int* __restrict__ ss2,
    const float* __restrict__ ns2, int NU, int nbU,
    const int* __restrict__ row_i, const int* __restrict__ ss1,
    const float* __restrict__ ns1, int NI,
    const unsigned short* __restrict__ wfrag,
    const float* __restrict__ b1, const float* __restrict__ b2,
    float* out_base)
{
    __shared__ __align__(16) unsigned short Ah[32 * 256];  // 16 KB
    __shared__ __align__(16) unsigned short Al[32 * 256];  // 16 KB
    __shared__ float sst[32];

    const float *featO, *featS, *ns;
    const int *row, *ss;
    float* out;
    int row0, nrows;
    if ((int)blockIdx.x < nbU) {
        featO = feat_user; featS = feat_item; row = row_u; ss = ss2; ns = ns2;
        out = out_base; row0 = blockIdx.x * 32; nrows = NU;
    } else {
        featO = feat_item; featS = feat_user; row = row_i; ss = ss1; ns = ns1;
        out = out_base + (size_t)NU * DD;
        row0 = (blockIdx.x - nbU) * 32; nrows = NI;
    }

    int t = threadIdx.x;
    int w = t >> 6;
    int lane = t & 63;
    char* pAh = (char*)Ah;
    char* pAl = (char*)Al;

    // ---- Phase G: gather + stage (8 rows per wave) ----
    for (int rr = 0; rr < 8; ++rr) {
        int r = w * 8 + rr;
        int grow = row0 + r;
        float2 acc = {0.f, 0.f};
        float sn = 0.f;
        float2 f2 = {0.f, 0.f};
        if (grow < nrows) {
            f2 = *(const float2*)(featO + (size_t)grow * DD + lane * 2);
            int beg = row[grow], end = row[grow + 1];
            int j = beg;
            for (; j + 4 <= end; j += 4) {       // 4 source rows in flight
                int s0 = ss[j], s1 = ss[j + 1], s2 = ss[j + 2], s3 = ss[j + 3];
                float n0 = ns[j],     n1 = ns[j + 1];
                float n2 = ns[j + 2], n3 = ns[j + 3];
                float2 v0 = *(const float2*)(featS + (size_t)s0 * DD + lane * 2);
                float2 v1 = *(const float2*)(featS + (size_t)s1 * DD + lane * 2);
                float2 v2 = *(const float2*)(featS + (size_t)s2 * DD + lane * 2);
                float2 v3 = *(const float2*)(featS + (size_t)s3 * DD + lane * 2);
                acc.x += n0 * v0.x + n1 * v1.x + n2 * v2.x + n3 * v3.x;
                acc.y += n0 * v0.y + n1 * v1.y + n2 * v2.y + n3 * v3.y;
                sn += n0 + n1 + n2 + n3;
            }
            for (; j < end; ++j) {
                int s0 = ss[j];
                float n0 = ns[j];
                float2 v0 = *(const float2*)(featS + (size_t)s0 * DD + lane * 2);
                acc.x += n0 * v0.x;
                acc.y += n0 * v0.y;
                sn += n0;
            }
        }
        float x0 = f2.x + acc.x, x1 = f2.y + acc.y;
        float y0 = f2.x * acc.x, y1 = f2.y * acc.y;
        unsigned int xh, xl, yh, yl;
        split2(x0, x1, xh, xl);
        split2(y0, y1, yh, yl);
        int swz = (r & 7) << 4;
        int rb = r * 512;
        int xo = rb + ((4 * lane) ^ swz);
        int yo = rb + ((256 + 4 * lane) ^ swz);
        *(unsigned int*)(pAh + xo) = xh;
        *(unsigned int*)(pAl + xo) = xl;
        *(unsigned int*)(pAh + yo) = yh;
        *(unsigned int*)(pAl + yo) = yl;
        if (lane == 0) sst[r] = sn;
    }
    __syncthreads();

    // ---- Phase 2: MFMA over K=256 (8 k-steps of 32) ----
    int r16 = lane & 15, g = lane >> 4;
    f32x4 acc00 = {0.f,0.f,0.f,0.f}, acc01 = {0.f,0.f,0.f,0.f};
    f32x4 acc10 = {0.f,0.f,0.f,0.f}, acc11 = {0.f,0.f,0.f,0.f};
    const char* cAh = (const char*)Ah;
    const char* cAl = (const char*)Al;
    int swzA = (r16 & 7) << 4;   // (r16+16)&7 == r16&7
    int ob0 = r16 * 512;
    int ob1 = (r16 + 16) * 512;

    #pragma unroll 2
    for (int ks = 0; ks < 8; ++ks) {
        int kb = ks * 64 + g * 16;
        int offx = kb ^ swzA;
        short8 a0h = *(const short8*)(cAh + ob0 + offx);
        short8 a0l = *(const short8*)(cAl + ob0 + offx);
        short8 a1h = *(const short8*)(cAh + ob1 + offx);
        short8 a1l = *(const short8*)(cAl + ob1 + offx);
        int mat = ks >> 2, ksm = ks & 3;
        const unsigned short* ph = wfrag + (size_t)mat * 32768;
        const unsigned short* pl = ph + 16384;
        int bo0 = ((ksm * 8 + w * 2) * 64 + lane) * 8;
        int bo1 = bo0 + 512;
        short8 b0h = *(const short8*)(ph + bo0);
        short8 b0l = *(const short8*)(pl + bo0);
        short8 b1h = *(const short8*)(ph + bo1);
        short8 b1l = *(const short8*)(pl + bo1);
        acc00 = __builtin_amdgcn_mfma_f32_16x16x32_bf16(a0h, b0h, acc00, 0, 0, 0);
        acc00 = __builtin_amdgcn_mfma_f32_16x16x32_bf16(a0h, b0l, acc00, 0, 0, 0);
        acc00 = __builtin_amdgcn_mfma_f32_16x16x32_bf16(a0l, b0h, acc00, 0, 0, 0);
        acc01 = __builtin_amdgcn_mfma_f32_16x16x32_bf16(a0h, b1h, acc01, 0, 0, 0);
        acc01 = __builtin_amdgcn_mfma_f32_16x16x32_bf16(a0h, b1l, acc01, 0, 0, 0);
        acc01 = __builtin_amdgcn_mfma_f32_16x16x32_bf16(a0l, b1h, acc01, 0, 0, 0);
        acc10 = __builtin_amdgcn_mfma_f32_16x16x32_bf16(a1h, b0h, acc10, 0, 0, 0);
        acc10 = __builtin_amdgcn_mfma_f32_16x16x32_bf16(a1h, b0l, acc10, 0, 0, 0);
        acc10 = __builtin_amdgcn_mfma_f32_16x16x32_bf16(a1l, b0h, acc10, 0, 0, 0);
        acc11 = __builtin_amdgcn_mfma_f32_16x16x32_bf16(a1h, b1h, acc11, 0, 0, 0);
        acc11 = __builtin_amdgcn_mfma_f32_16x16x32_bf16(a1h, b1l, acc11, 0, 0, 0);
        acc11 = __builtin_amdgcn_mfma_f32_16x16x32_bf16(a1l, b1h, acc11, 0, 0, 0);
    }
    __syncthreads();

    // ---- Phase 3: h -> LDS (reuse Ah/Al as padded f32 buf), epilogue ----
    float* hbuf = (float*)Ah;    // 32 x HS f32 = 16.9 KB (spans Ah into Al)
    #pragma unroll
    for (int j = 0; j < 4; ++j) {
        int rA = g * 4 + j;
        hbuf[rA * HS        + (w * 32 + r16)]      = acc00[j];
        hbuf[rA * HS        + (w * 32 + 16 + r16)] = acc01[j];
        hbuf[(16 + rA) * HS + (w * 32 + r16)]      = acc10[j];
        hbuf[(16 + rA) * HS + (w * 32 + 16 + r16)] = acc11[j];
    }
    __syncthreads();

    int c0 = t & 63, c1 = c0 + 64, rg = t >> 6;
    float b1c0 = b1[c0], b1c1 = b1[c1];
    float b2c0 = b2[c0], b2c1 = b2[c1];
    #pragma unroll
    for (int rr = 0; rr < 8; ++rr) {
        int lr = rg * 8 + rr;
        int row_ = row0 + lr;
        if (row_ < nrows) {
            float s = sst[lr];
            float h0 = hbuf[lr * HS + c0] + (1.0f + s) * b1c0 + s * b2c0;
            float h1 = hbuf[lr * HS + c1] + (1.0f + s) * b1c1 + s * b2c1;
            h0 = h0 >= 0.f ? h0 : 0.2f * h0;
            h1 = h1 >= 0.f ? h1 : 0.2f * h1;
            float loc = h0 * h0 + h1 * h1;
            #pragma unroll
            for (int m = 32; m >= 1; m >>= 1) loc += __shfl_xor(loc, m, 64);
            float inv = 1.0f / fmaxf(sqrtf(loc), 1e-12f);
            __builtin_nontemporal_store(h0 * inv, out + (size_t)row_ * DD + c0);
            __builtin_nontemporal_store(h1 * inv, out + (size_t)row_ * DD + c1);
        }
    }
}

// ---------------- fp32 finish (tier2/3 fallback) ----------------

__global__ __launch_bounds__(256) void finish_kernel(
    const float* __restrict__ feat,
    const float* agg,
    const float* __restrict__ ssum,
    const float* __restrict__ W1,
    const float* __restrict__ b1,
    const float* __restrict__ W2,
    const float* __restrict__ b2,
    float* out,
    int nrows)
{
    __shared__ float xs[32][DD];
    __shared__ float ys[32][DD];
    int row0 = blockIdx.x * 32;
    int tid = threadIdx.x;

    for (int i = tid; i < 32 * (DD / 4); i += 256) {
        int r = i >> 5;
        int c4 = (i & 31) * 4;
        int row = row0 + r;
        if (row < nrows) {
            float4 f = *(const float4*)(feat + (size_t)row * DD + c4);
            float4 a = *(const float4*)(agg  + (size_t)row * DD + c4);
            float4 x, y;
            x.x = f.x + a.x; x.y = f.y + a.y; x.z = f.z + a.z; x.w = f.w + a.w;
            y.x = f.x * a.x; y.y = f.y * a.y; y.z = f.z * a.z; y.w = f.w * a.w;
            *(float4*)&xs[r][c4] = x;
            *(float4*)&ys[r][c4] = y;
        }
    }
    __syncthreads();

    int c0 = tid & 63;
    int rg = tid >> 6;
    int c1 = c0 + 64;

    float acc[8][2] = {{0.f,0.f},{0.f,0.f},{0.f,0.f},{0.f,0.f},
                       {0.f,0.f},{0.f,0.f},{0.f,0.f},{0.f,0.f}};
    for (int k = 0; k < DD; k += 4) {
        float w1a[4], w1b[4], w2a[4], w2b[4];
        #pragma unroll
        for (int kk = 0; kk < 4; ++kk) {
            const float* wr1 = W1 + (size_t)(k + kk) * DD;
            const float* wr2 = W2 + (size_t)(k + kk) * DD;
            w1a[kk] = wr1[c0]; w1b[kk] = wr1[c1];
            w2a[kk] = wr2[c0]; w2b[kk] = wr2[c1];
        }
        #pragma unroll
        for (int r = 0; r < 8; ++r) {
            float4 xv = *(const float4*)&xs[rg * 8 + r][k];
            float4 yv = *(const float4*)&ys[rg * 8 + r][k];
            acc[r][0] += xv.x*w1a[0] + xv.y*w1a[1] + xv.z*w1a[2] + xv.w*w1a[3]
                       + yv.x*w2a[0] + yv.y*w2a[1] + yv.z*w2a[2] + yv.w*w2a[3];
            acc[r][1] += xv.x*w1b[0] + xv.y*w1b[1] + xv.z*w1b[2] + xv.w*w1b[3]
                       + yv.x*w2b[0] + yv.y*w2b[1] + yv.z*w2b[2] + yv.w*w2b[3];
        }
    }

    float b1c0 = b1[c0], b1c1 = b1[c1];
    float b2c0 = b2[c0], b2c1 = b2[c1];

    #pragma unroll
    for (int r = 0; r < 8; ++r) {
        int row = row0 + rg * 8 + r;
        if (row < nrows) {
            float s = ssum[row];
            float h0 = acc[r][0] + (1.0f + s) * b1c0 + s * b2c0;
            float h1 = acc[r][1] + (1.0f + s) * b1c1 + s * b2c1;
            h0 = h0 >= 0.f ? h0 : 0.2f * h0;
            h1 = h1 >= 0.f ? h1 : 0.2f * h1;
            float loc = h0 * h0 + h1 * h1;
            #pragma unroll
            for (int m = 32; m >= 1; m >>= 1) loc += __shfl_xor(loc, m, 64);
            float inv = 1.0f / fmaxf(sqrtf(loc), 1e-12f);
            out[(size_t)row * DD + c0] = h0 * inv;
            out[(size_t)row * DD + c1] = h1 * inv;
        }
    }
}

extern "C" void kernel_launch(void* const* d_in, const int* in_sizes, int n_in,
                              void* d_out, int out_size, void* d_ws, size_t ws_size,
                              hipStream_t stream) {
    const float* feat_user = (const float*)d_in[0];
    const float* feat_item = (const float*)d_in[1];
    const float* W1        = (const float*)d_in[2];
    const float* b1        = (const float*)d_in[3];
    const float* W2        = (const float*)d_in[4];
    const float* b2        = (const float*)d_in[5];
    const float* norm_u2i  = (const float*)d_in[6];
    const float* norm_i2u  = (const float*)d_in[7];
    const int* eus = (const int*)d_in[8];
    const int* eud = (const int*)d_in[9];
    const int* eis = (const int*)d_in[10];
    const int* eid = (const int*)d_in[11];

    int NU = in_sizes[0] / DD;
    int NI = in_sizes[1] / DD;
    int E1 = in_sizes[8];
    int E2 = in_sizes[10];
    float* out = (float*)d_out;

    int nb0 = (NI + SCAN_TILE - 1) / SCAN_TILE;
    int nb1 = (NU + SCAN_TILE - 1) / SCAN_TILE;
    int nbU = (NU + 31) / 32;
    int nbI = (NI + 31) / 32;

    size_t wfrag_bytes = 131072;   // 4 planes x 32 KB
    size_t need_pg   = wfrag_bytes +
                       ((size_t)3 * NU + 3 * NI + 2 * E1 + 2 * E2 + 2
                        + nb0 + nb1) * sizeof(int);

    int eb = (int)(((long long)E1 + E2 + 255) / 256);

    if (ws_size >= need_pg) {
        // ---- Tier 1: CSR + pre-gathered + fused gather/MFMA finish ----
        unsigned short* wfrag = (unsigned short*)d_ws;   // 128 KB, 16B-aligned
        int* cur_i = (int*)((char*)d_ws + wfrag_bytes);  // NI
        int* cur_u = cur_i + NI;            // NU
        int* row_i = cur_u + NU;            // NI+1
        int* row_u = row_i + NI + 1;        // NU+1
        int* ss1   = row_u + NU + 1;        // E1
        int* ss2   = ss1 + E1;              // E2
        float* ns1 = (float*)(ss2 + E2);    // E1
        float* ns2 = ns1 + E1;              // E2
        int* bsum  = (int*)(ns2 + E2);      // nb0+nb1

        wprep_kernel<<<16, 256, 0, stream>>>(W1, W2, wfrag);

        hipMemsetAsync(cur_i, 0, (size_t)(NI + NU) * sizeof(int), stream);

        count_kernel<<<eb, 256, 0, stream>>>(eud, E1, cur_i, eid, E2, cur_u);
        scanA_kernel<<<nb0 + nb1, 256, 0, stream>>>(cur_i, NI, cur_u, NU,
                                                    bsum, nb0);
        scanB_kernel<<<1, 256, 0, stream>>>(bsum, nb0, nb1,
                                            row_i, NI, row_u, NU);
        scanC_kernel<<<nb0 + nb1, 256, 0, stream>>>(cur_i, row_i, NI,
                                                    cur_u, row_u, NU,
                                                    bsum, nb0);
        fill_pg_kernel<<<eb, 256, 0, stream>>>(
            eud, eus, norm_u2i, E1, cur_i, ss1, ns1,
            eid, eis, norm_i2u, E2, cur_u, ss2, ns2);

        fused_kernel<<<nbU + nbI, 256, 0, stream>>>(
            feat_user, feat_item,
            row_u, ss2, ns2, NU, nbU,
            row_i, ss1, ns1, NI,
            wfrag, b1, b2, out);
    } else {
        // ---- Fallback: atomic scatter + fp32 finish ----
        float* agg_user = out;
        float* agg_item = out + (size_t)NU * DD;
        float* s_user = (float*)d_ws;
        float* s_item = s_user + NU;

        hipMemsetAsync(out, 0, (size_t)out_size * sizeof(float), stream);
        hipMemsetAsync(d_ws, 0, (size_t)(NU + NI) * sizeof(float), stream);

        int b1n = (int)(((long long)E1 * 64 + 255) / 256);
        scatter_kernel<<<b1n, 256, 0, stream>>>(feat_user, eus, eud, norm_u2i,
                                                agg_item, s_item, E1);
        int b2n = (int)(((long long)E2 * 64 + 255) / 256);
        scatter_kernel<<<b2n, 256, 0, stream>>>(feat_item, eis, eid, norm_i2u,
                                                agg_user, s_user, E2);

        finish_kernel<<<nbU, 256, 0, stream>>>(
            feat_user, agg_user, s_user, W1, b1, W2, b2, out, NU);
        finish_kernel<<<nbI, 256, 0, stream>>>(
            feat_item, agg_item, s_item, W1, b1, W2, b2,
            out + (size_t)NU * DD, NI);
    }
}

// Round 5
// 379.608 us; speedup vs baseline: 2.2147x; 1.1027x over previous
//
#include <hip/hip_runtime.h>

#define DD 128
#define SCAN_TILE 1024   // 256 threads x 4 elements per block
#define HS 132           // padded hbuf stride (floats): 4-way -> 2-way banks
#define FR 16            // rows per fused block (16 -> 16.4 KB LDS -> 8 blk/CU)

typedef __attribute__((ext_vector_type(8))) short short8;
typedef __attribute__((ext_vector_type(4))) float f32x4;

// bf16 round-to-nearest-even split helpers
__device__ inline unsigned short f2bf_rne(float f) {
    unsigned int u = __float_as_uint(f);
    unsigned int r = u + 0x7FFFu + ((u >> 16) & 1u);
    return (unsigned short)(r >> 16);
}
__device__ inline float bf2f(unsigned short h) {
    return __uint_as_float(((unsigned int)h) << 16);
}
// split (a,b) into packed bf16 hi pair + lo pair (residual)
__device__ inline void split2(float a, float b, unsigned int& hi, unsigned int& lo) {
    unsigned short ha = f2bf_rne(a), hb = f2bf_rne(b);
    float la = a - bf2f(ha), lb = b - bf2f(hb);
    hi = (unsigned int)ha | ((unsigned int)hb << 16);
    lo = (unsigned int)f2bf_rne(la) | ((unsigned int)f2bf_rne(lb) << 16);
}

// ---------------- count (+ merged wprep) ----------------
// Blocks [0,16): pre-split W1/W2 into MFMA B-fragment planes.
// Blocks [16, 16+eb): histogram edge destinations (both directions).
// Planes (each 16384 ushorts = 32 KB): 0=W1h 1=W1l 2=W2h 3=W2l.
// B-frag layout (16x16x32 bf16): lane l=16g+c holds B[k0+8g+i][cf*16+c].
__global__ __launch_bounds__(256) void count_wprep_kernel(
    const int* __restrict__ dst1, int E1, int* deg1,
    const int* __restrict__ dst2, int E2, int* deg2,
    const float* __restrict__ W1, const float* __restrict__ W2,
    unsigned short* wfrag)
{
    int b = blockIdx.x;
    if (b < 16) {
        int t = b * 256 + threadIdx.x;     // 4096 threads
        int lane = t & 63;
        int cf   = (t >> 6) & 7;
        int ksm  = (t >> 9) & 3;
        int mat  = t >> 11;
        const float* W = mat ? W2 : W1;
        int g = lane >> 4, c = lane & 15;
        int n = cf * 16 + c;
        unsigned int hi[4], lo[4];
        #pragma unroll
        for (int p = 0; p < 4; ++p) {
            int k0 = ksm * 32 + g * 8 + p * 2;
            float v0 = W[(size_t)k0 * DD + n];
            float v1 = W[(size_t)(k0 + 1) * DD + n];
            split2(v0, v1, hi[p], lo[p]);
        }
        unsigned short* dh = wfrag + (size_t)mat * 32768
                           + ((size_t)(ksm * 8 + cf) * 64 + lane) * 8;
        unsigned short* dl = dh + 16384;
        *(uint4*)dh = make_uint4(hi[0], hi[1], hi[2], hi[3]);
        *(uint4*)dl = make_uint4(lo[0], lo[1], lo[2], lo[3]);
        return;
    }
    int t = (b - 16) * 256 + threadIdx.x;
    if (t < E1) {
        atomicAdd(deg1 + dst1[t], 1);
    } else if (t - E1 < E2) {
        atomicAdd(deg2 + dst2[t - E1], 1);
    }
}

// ---- Multi-block exclusive scan over the two degree arrays ----
__global__ __launch_bounds__(256) void scanA_kernel(
    const int* __restrict__ cur_i, int NI,
    const int* __restrict__ cur_u, int NU,
    int* bsum, int nb0)
{
    int b = blockIdx.x;
    const int* cur;
    int N, base;
    if (b < nb0) { cur = cur_i; N = NI; base = b * SCAN_TILE; }
    else         { cur = cur_u; N = NU; base = (b - nb0) * SCAN_TILE; }
    int t = threadIdx.x;
    int idx0 = base + t * 4;
    int s = 0;
    #pragma unroll
    for (int k = 0; k < 4; ++k) {
        int idx = idx0 + k;
        if (idx < N) s += cur[idx];
    }
    __shared__ int red[256];
    red[t] = s;
    __syncthreads();
    for (int o = 128; o >= 1; o >>= 1) {
        if (t < o) red[t] += red[t + o];
        __syncthreads();
    }
    if (t == 0) bsum[b] = red[0];
}

__device__ int block_exscan_inplace(int* a, int n)
{
    __shared__ int sh[256];
    int t = threadIdx.x;
    int carry = 0;
    for (int base = 0; base < n; base += 256) {
        int v = (base + t < n) ? a[base + t] : 0;
        sh[t] = v;
        __syncthreads();
        for (int off = 1; off < 256; off <<= 1) {
            int u = (t >= off) ? sh[t - off] : 0;
            __syncthreads();
            sh[t] += u;
            __syncthreads();
        }
        if (base + t < n) a[base + t] = carry + sh[t] - v;  // exclusive
        int csum = sh[255];
        __syncthreads();
        carry += csum;
    }
    return carry;
}

__global__ __launch_bounds__(256) void scanB_kernel(
    int* bsum, int nb0, int nb1,
    int* row_i, int NI, int* row_u, int NU)
{
    int tot0 = block_exscan_inplace(bsum, nb0);
    __syncthreads();
    int tot1 = block_exscan_inplace(bsum + nb0, nb1);
    if (threadIdx.x == 0) {
        row_i[NI] = tot0;
        row_u[NU] = tot1;
    }
}

__global__ __launch_bounds__(256) void scanC_kernel(
    int* cur_i, int* row_i, int NI,
    int* cur_u, int* row_u, int NU,
    const int* __restrict__ bsum, int nb0)
{
    int b = blockIdx.x;
    int off = bsum[b];
    int* cur; int* row;
    int N, base;
    if (b < nb0) { cur = cur_i; row = row_i; N = NI; base = b * SCAN_TILE; }
    else         { cur = cur_u; row = row_u; N = NU; base = (b - nb0) * SCAN_TILE; }
    int t = threadIdx.x;
    int idx0 = base + t * 4;
    int v[4];
    int s = 0;
    #pragma unroll
    for (int k = 0; k < 4; ++k) {
        int idx = idx0 + k;
        v[k] = (idx < N) ? cur[idx] : 0;
        s += v[k];
    }
    __shared__ int sh[256];
    sh[t] = s;
    __syncthreads();
    for (int o = 1; o < 256; o <<= 1) {
        int u = (t >= o) ? sh[t - o] : 0;
        __syncthreads();
        sh[t] += u;
        __syncthreads();
    }
    int run = off + sh[t] - s;
    #pragma unroll
    for (int k = 0; k < 4; ++k) {
        int idx = idx0 + k;
        if (idx < N) {
            row[idx] = run;
            cur[idx] = run;
            run += v[k];
        }
    }
}

// Fill: scatter PACKED (src, norm) as int2 into dst-grouped order.
__global__ __launch_bounds__(256) void fill_pg_kernel(
    const int* __restrict__ dst1, const int* __restrict__ src1,
    const float* __restrict__ norm1, int E1, int* cur1, int2* esn1,
    const int* __restrict__ dst2, const int* __restrict__ src2,
    const float* __restrict__ norm2, int E2, int* cur2, int2* esn2)
{
    int t = blockIdx.x * 256 + threadIdx.x;
    if (t < E1) {
        int pos = atomicAdd(cur1 + dst1[t], 1);
        esn1[pos] = make_int2(src1[t], __float_as_int(norm1[t]));
    } else if (t - E1 < E2) {
        int e = t - E1;
        int pos = atomicAdd(cur2 + dst2[e], 1);
        esn2[pos] = make_int2(src2[e], __float_as_int(norm2[e]));
    }
}

// ---------------- Tier 3 fallback: atomic scatter ----------------

__global__ __launch_bounds__(256) void scatter_kernel(
    const float* __restrict__ feat_src,
    const int* __restrict__ src,
    const int* __restrict__ dst,
    const float* __restrict__ norm,
    float* agg,
    float* ssum,
    int E)
{
    int gw = (int)((blockIdx.x * 256u + threadIdx.x) >> 6);
    int lane = threadIdx.x & 63;
    if (gw >= E) return;
    int si = src[gw];
    int di = dst[gw];
    float nv = norm[gw];
    float2 v = *(const float2*)(feat_src + (size_t)si * DD + lane * 2);
    float* ap = agg + (size_t)di * DD + lane * 2;
    unsafeAtomicAdd(ap,     v.x * nv);
    unsafeAtomicAdd(ap + 1, v.y * nv);
    if (lane == 0) unsafeAtomicAdd(ssum + di, nv);
}

// ---------------- Fused gather + MFMA finish (16 rows/block) ----------------
// Phase G: each of 4 waves gathers 4 rows (CSR edge loop, 2 cols/lane),
// computes x=f+a, y=f*a, splits to bf16 hi/lo, writes into XOR-swizzled
// LDS A-tiles. Phase 2: split-bf16 MFMA (3/k-step). Phase 3: epilogue.
// 16.4 KB LDS + VGPR<64 -> 8 blocks/CU = 32 waves/CU during gather.
__global__ __launch_bounds__(256) void fused_kernel(
    const float* __restrict__ feat_user, const float* __restrict__ feat_item,
    const int* __restrict__ row_u, const int2* __restrict__ esnU,
    int NU, int nbU,
    const int* __restrict__ row_i, const int2* __restrict__ esnI, int NI,
    const unsigned short* __restrict__ wfrag,
    const float* __restrict__ b1, const float* __restrict__ b2,
    float* out_base)
{
    __shared__ __align__(16) char smem[FR * 512 * 2];   // 16 KB: Ah | Al
    __shared__ float sst[FR];

    const float *featO, *featS;
    const int *row;
    const int2 *esn;
    float* out;
    int row0, nrows;
    if ((int)blockIdx.x < nbU) {
        featO = feat_user; featS = feat_item; row = row_u; esn = esnU;
        out = out_base; row0 = blockIdx.x * FR; nrows = NU;
    } else {
        featO = feat_item; featS = feat_user; row = row_i; esn = esnI;
        out = out_base + (size_t)NU * DD;
        row0 = (blockIdx.x - nbU) * FR; nrows = NI;
    }

    int t = threadIdx.x;
    int w = t >> 6;
    int lane = t & 63;
    char* pAh = smem;
    char* pAl = smem + FR * 512;

    // ---- Phase G: gather + stage (4 rows per wave) ----
    for (int rr = 0; rr < 4; ++rr) {
        int r = w * 4 + rr;
        int grow = row0 + r;
        float2 acc = {0.f, 0.f};
        float sn = 0.f;
        float2 f2 = {0.f, 0.f};
        if (grow < nrows) {
            f2 = *(const float2*)(featO + (size_t)grow * DD + lane * 2);
            int beg = row[grow], end = row[grow + 1];
            int j = beg;
            for (; j + 4 <= end; j += 4) {       // 4 source rows in flight
                int2 e0 = esn[j],     e1 = esn[j + 1];
                int2 e2 = esn[j + 2], e3 = esn[j + 3];
                float2 v0 = *(const float2*)(featS + (size_t)e0.x * DD + lane * 2);
                float2 v1 = *(const float2*)(featS + (size_t)e1.x * DD + lane * 2);
                float2 v2 = *(const float2*)(featS + (size_t)e2.x * DD + lane * 2);
                float2 v3 = *(const float2*)(featS + (size_t)e3.x * DD + lane * 2);
                float n0 = __int_as_float(e0.y), n1 = __int_as_float(e1.y);
                float n2 = __int_as_float(e2.y), n3 = __int_as_float(e3.y);
                acc.x += n0 * v0.x + n1 * v1.x + n2 * v2.x + n3 * v3.x;
                acc.y += n0 * v0.y + n1 * v1.y + n2 * v2.y + n3 * v3.y;
                sn += n0 + n1 + n2 + n3;
            }
            for (; j < end; ++j) {
                int2 e0 = esn[j];
                float n0 = __int_as_float(e0.y);
                float2 v0 = *(const float2*)(featS + (size_t)e0.x * DD + lane * 2);
                acc.x += n0 * v0.x;
                acc.y += n0 * v0.y;
                sn += n0;
            }
        }
        float x0 = f2.x + acc.x, x1 = f2.y + acc.y;
        float y0 = f2.x * acc.x, y1 = f2.y * acc.y;
        unsigned int xh, xl, yh, yl;
        split2(x0, x1, xh, xl);
        split2(y0, y1, yh, yl);
        int swz = (r & 7) << 4;
        int rb = r * 512;
        int xo = rb + ((4 * lane) ^ swz);
        int yo = rb + ((256 + 4 * lane) ^ swz);
        *(unsigned int*)(pAh + xo) = xh;
        *(unsigned int*)(pAl + xo) = xl;
        *(unsigned int*)(pAh + yo) = yh;
        *(unsigned int*)(pAl + yo) = yl;
        if (lane == 0) sst[r] = sn;
    }
    __syncthreads();

    // ---- Phase 2: MFMA over K=256 (8 k-steps of 32) ----
    int r16 = lane & 15, g = lane >> 4;
    f32x4 acc0 = {0.f,0.f,0.f,0.f}, acc1 = {0.f,0.f,0.f,0.f};
    const char* cAh = (const char*)pAh;
    const char* cAl = (const char*)pAl;
    int swzA = (r16 & 7) << 4;
    int ob0 = r16 * 512;

    #pragma unroll 2
    for (int ks = 0; ks < 8; ++ks) {
        int offx = (ks * 64 + g * 16) ^ swzA;
        short8 a0h = *(const short8*)(cAh + ob0 + offx);
        short8 a0l = *(const short8*)(cAl + ob0 + offx);
        int mat = ks >> 2, ksm = ks & 3;
        const unsigned short* ph = wfrag + (size_t)mat * 32768;
        const unsigned short* pl = ph + 16384;
        int bo0 = ((ksm * 8 + w * 2) * 64 + lane) * 8;
        int bo1 = bo0 + 512;
        short8 b0h = *(const short8*)(ph + bo0);
        short8 b0l = *(const short8*)(pl + bo0);
        short8 b1h = *(const short8*)(ph + bo1);
        short8 b1l = *(const short8*)(pl + bo1);
        acc0 = __builtin_amdgcn_mfma_f32_16x16x32_bf16(a0h, b0h, acc0, 0, 0, 0);
        acc0 = __builtin_amdgcn_mfma_f32_16x16x32_bf16(a0h, b0l, acc0, 0, 0, 0);
        acc0 = __builtin_amdgcn_mfma_f32_16x16x32_bf16(a0l, b0h, acc0, 0, 0, 0);
        acc1 = __builtin_amdgcn_mfma_f32_16x16x32_bf16(a0h, b1h, acc1, 0, 0, 0);
        acc1 = __builtin_amdgcn_mfma_f32_16x16x32_bf16(a0h, b1l, acc1, 0, 0, 0);
        acc1 = __builtin_amdgcn_mfma_f32_16x16x32_bf16(a0l, b1h, acc1, 0, 0, 0);
    }
    __syncthreads();

    // ---- Phase 3: h -> LDS (reuse smem as padded f32 buf), epilogue ----
    float* hbuf = (float*)smem;    // FR x HS f32 = 8.45 KB
    #pragma unroll
    for (int j = 0; j < 4; ++j) {
        int rA = g * 4 + j;
        hbuf[rA * HS + (w * 32 + r16)]      = acc0[j];
        hbuf[rA * HS + (w * 32 + 16 + r16)] = acc1[j];
    }
    __syncthreads();

    int c0 = t & 63, c1 = c0 + 64, rg = t >> 6;
    float b1c0 = b1[c0], b1c1 = b1[c1];
    float b2c0 = b2[c0], b2c1 = b2[c1];
    #pragma unroll
    for (int rr = 0; rr < 4; ++rr) {
        int lr = rg * 4 + rr;
        int row_ = row0 + lr;
        if (row_ < nrows) {
            float s = sst[lr];
            float h0 = hbuf[lr * HS + c0] + (1.0f + s) * b1c0 + s * b2c0;
            float h1 = hbuf[lr * HS + c1] + (1.0f + s) * b1c1 + s * b2c1;
            h0 = h0 >= 0.f ? h0 : 0.2f * h0;
            h1 = h1 >= 0.f ? h1 : 0.2f * h1;
            float loc = h0 * h0 + h1 * h1;
            #pragma unroll
            for (int m = 32; m >= 1; m >>= 1) loc += __shfl_xor(loc, m, 64);
            float inv = 1.0f / fmaxf(sqrtf(loc), 1e-12f);
            __builtin_nontemporal_store(h0 * inv, out + (size_t)row_ * DD + c0);
            __builtin_nontemporal_store(h1 * inv, out + (size_t)row_ * DD + c1);
        }
    }
}

// ---------------- fp32 finish (fallback) ----------------

__global__ __launch_bounds__(256) void finish_kernel(
    const float* __restrict__ feat,
    const float* agg,
    const float* __restrict__ ssum,
    const float* __restrict__ W1,
    const float* __restrict__ b1,
    const float* __restrict__ W2,
    const float* __restrict__ b2,
    float* out,
    int nrows)
{
    __shared__ float xs[32][DD];
    __shared__ float ys[32][DD];
    int row0 = blockIdx.x * 32;
    int tid = threadIdx.x;

    for (int i = tid; i < 32 * (DD / 4); i += 256) {
        int r = i >> 5;
        int c4 = (i & 31) * 4;
        int row = row0 + r;
        if (row < nrows) {
            float4 f = *(const float4*)(feat + (size_t)row * DD + c4);
            float4 a = *(const float4*)(agg  + (size_t)row * DD + c4);
            float4 x, y;
            x.x = f.x + a.x; x.y = f.y + a.y; x.z = f.z + a.z; x.w = f.w + a.w;
            y.x = f.x * a.x; y.y = f.y * a.y; y.z = f.z * a.z; y.w = f.w * a.w;
            *(float4*)&xs[r][c4] = x;
            *(float4*)&ys[r][c4] = y;
        }
    }
    __syncthreads();

    int c0 = tid & 63;
    int rg = tid >> 6;
    int c1 = c0 + 64;

    float acc[8][2] = {{0.f,0.f},{0.f,0.f},{0.f,0.f},{0.f,0.f},
                       {0.f,0.f},{0.f,0.f},{0.f,0.f},{0.f,0.f}};
    for (int k = 0; k < DD; k += 4) {
        float w1a[4], w1b[4], w2a[4], w2b[4];
        #pragma unroll
        for (int kk = 0; kk < 4; ++kk) {
            const float* wr1 = W1 + (size_t)(k + kk) * DD;
            const float* wr2 = W2 + (size_t)(k + kk) * DD;
            w1a[kk] = wr1[c0]; w1b[kk] = wr1[c1];
            w2a[kk] = wr2[c0]; w2b[kk] = wr2[c1];
        }
        #pragma unroll
        for (int r = 0; r < 8; ++r) {
            float4 xv = *(const float4*)&xs[rg * 8 + r][k];
            float4 yv = *(const float4*)&ys[rg * 8 + r][k];
            acc[r][0] += xv.x*w1a[0] + xv.y*w1a[1] + xv.z*w1a[2] + xv.w*w1a[3]
                       + yv.x*w2a[0] + yv.y*w2a[1] + yv.z*w2a[2] + yv.w*w2a[3];
            acc[r][1] += xv.x*w1b[0] + xv.y*w1b[1] + xv.z*w1b[2] + xv.w*w1b[3]
                       + yv.x*w2b[0] + yv.y*w2b[1] + yv.z*w2b[2] + yv.w*w2b[3];
        }
    }

    float b1c0 = b1[c0], b1c1 = b1[c1];
    float b2c0 = b2[c0], b2c1 = b2[c1];

    #pragma unroll
    for (int r = 0; r < 8; ++r) {
        int row = row0 + rg * 8 + r;
        if (row < nrows) {
            float s = ssum[row];
            float h0 = acc[r][0] + (1.0f + s) * b1c0 + s * b2c0;
            float h1 = acc[r][1] + (1.0f + s) * b1c1 + s * b2c1;
            h0 = h0 >= 0.f ? h0 : 0.2f * h0;
            h1 = h1 >= 0.f ? h1 : 0.2f * h1;
            float loc = h0 * h0 + h1 * h1;
            #pragma unroll
            for (int m = 32; m >= 1; m >>= 1) loc += __shfl_xor(loc, m, 64);
            float inv = 1.0f / fmaxf(sqrtf(loc), 1e-12f);
            out[(size_t)row * DD + c0] = h0 * inv;
            out[(size_t)row * DD + c1] = h1 * inv;
        }
    }
}

extern "C" void kernel_launch(void* const* d_in, const int* in_sizes, int n_in,
                              void* d_out, int out_size, void* d_ws, size_t ws_size,
                              hipStream_t stream) {
    const float* feat_user = (const float*)d_in[0];
    const float* feat_item = (const float*)d_in[1];
    const float* W1        = (const float*)d_in[2];
    const float* b1        = (const float*)d_in[3];
    const float* W2        = (const float*)d_in[4];
    const float* b2        = (const float*)d_in[5];
    const float* norm_u2i  = (const float*)d_in[6];
    const float* norm_i2u  = (const float*)d_in[7];
    const int* eus = (const int*)d_in[8];
    const int* eud = (const int*)d_in[9];
    const int* eis = (const int*)d_in[10];
    const int* eid = (const int*)d_in[11];

    int NU = in_sizes[0] / DD;
    int NI = in_sizes[1] / DD;
    int E1 = in_sizes[8];
    int E2 = in_sizes[10];
    float* out = (float*)d_out;

    int nb0 = (NI + SCAN_TILE - 1) / SCAN_TILE;
    int nb1 = (NU + SCAN_TILE - 1) / SCAN_TILE;
    int nbU = (NU + FR - 1) / FR;
    int nbI = (NI + FR - 1) / FR;

    size_t wfrag_bytes = 131072;   // 4 planes x 32 KB
    size_t need_pg   = wfrag_bytes + 64 /*align slack*/ +
                       ((size_t)3 * NU + 3 * NI + 2 * E1 + 2 * E2 + 2
                        + nb0 + nb1) * sizeof(int);

    int eb = (int)(((long long)E1 + E2 + 255) / 256);

    if (ws_size >= need_pg) {
        // ---- Tier 1: CSR + packed pre-gather + fused gather/MFMA finish ----
        unsigned short* wfrag = (unsigned short*)d_ws;   // 128 KB
        int* cur_i = (int*)((char*)d_ws + wfrag_bytes);  // NI
        int* cur_u = cur_i + NI;            // NU
        int* row_i = cur_u + NU;            // NI+1
        int* row_u = row_i + NI + 1;        // NU+1
        int* pend  = row_u + NU + 1;
        int2* esn1 = (int2*)(((uintptr_t)pend + 15) & ~(uintptr_t)15);  // E1
        int2* esn2 = esn1 + E1;             // E2
        int* bsum  = (int*)(esn2 + E2);     // nb0+nb1

        hipMemsetAsync(cur_i, 0, (size_t)(NI + NU) * sizeof(int), stream);

        count_wprep_kernel<<<16 + eb, 256, 0, stream>>>(
            eud, E1, cur_i, eid, E2, cur_u, W1, W2, wfrag);
        scanA_kernel<<<nb0 + nb1, 256, 0, stream>>>(cur_i, NI, cur_u, NU,
                                                    bsum, nb0);
        scanB_kernel<<<1, 256, 0, stream>>>(bsum, nb0, nb1,
                                            row_i, NI, row_u, NU);
        scanC_kernel<<<nb0 + nb1, 256, 0, stream>>>(cur_i, row_i, NI,
                                                    cur_u, row_u, NU,
                                                    bsum, nb0);
        fill_pg_kernel<<<eb, 256, 0, stream>>>(
            eud, eus, norm_u2i, E1, cur_i, esn1,
            eid, eis, norm_i2u, E2, cur_u, esn2);

        fused_kernel<<<nbU + nbI, 256, 0, stream>>>(
            feat_user, feat_item,
            row_u, esn2, NU, nbU,
            row_i, esn1, NI,
            wfrag, b1, b2, out);
    } else {
        // ---- Fallback: atomic scatter + fp32 finish ----
        float* agg_user = out;
        float* agg_item = out + (size_t)NU * DD;
        float* s_user = (float*)d_ws;
        float* s_item = s_user + NU;

        hipMemsetAsync(out, 0, (size_t)out_size * sizeof(float), stream);
        hipMemsetAsync(d_ws, 0, (size_t)(NU + NI) * sizeof(float), stream);

        int b1n = (int)(((long long)E1 * 64 + 255) / 256);
        scatter_kernel<<<b1n, 256, 0, stream>>>(feat_user, eus, eud, norm_u2i,
                                                agg_item, s_item, E1);
        int b2n = (int)(((long long)E2 * 64 + 255) / 256);
        scatter_kernel<<<b2n, 256, 0, stream>>>(feat_item, eis, eid, norm_i2u,
                                                agg_user, s_user, E2);

        finish_kernel<<<(NU + 31) / 32, 256, 0, stream>>>(
            feat_user, agg_user, s_user, W1, b1, W2, b2, out, NU);
        finish_kernel<<<(NI + 31) / 32, 256, 0, stream>>>(
            feat_item, agg_item, s_item, W1, b1, W2, b2,
            out + (size_t)NU * DD, NI);
    }
}

// Round 7
// 374.066 us; speedup vs baseline: 2.2475x; 1.0148x over previous
//
#include <hip/hip_runtime.h>

#define DD 128
#define SCAN_TILE 1024   // 256 threads x 4 elements per block
#define HS 136           // padded hbuf stride (floats): clean 2-way banks
#define FR 16            // rows per fused block (16 -> 16.4 KB LDS -> 8 blk/CU)

typedef __attribute__((ext_vector_type(8))) short short8;
typedef __attribute__((ext_vector_type(4))) float f32x4;
typedef __attribute__((ext_vector_type(2))) float f32x2;

// bf16 round-to-nearest-even split helpers
__device__ inline unsigned short f2bf_rne(float f) {
    unsigned int u = __float_as_uint(f);
    unsigned int r = u + 0x7FFFu + ((u >> 16) & 1u);
    return (unsigned short)(r >> 16);
}
__device__ inline float bf2f(unsigned short h) {
    return __uint_as_float(((unsigned int)h) << 16);
}
// split (a,b) into packed bf16 hi pair + lo pair (residual)
__device__ inline void split2(float a, float b, unsigned int& hi, unsigned int& lo) {
    unsigned short ha = f2bf_rne(a), hb = f2bf_rne(b);
    float la = a - bf2f(ha), lb = b - bf2f(hb);
    hi = (unsigned int)ha | ((unsigned int)hb << 16);
    lo = (unsigned int)f2bf_rne(la) | ((unsigned int)f2bf_rne(lb) << 16);
}

// ---------------- count (+ merged wprep) ----------------
// Blocks [0,16): pre-split W1/W2 into MFMA B-fragment planes.
// Blocks [16, 16+eb): histogram edge destinations (both directions).
__global__ __launch_bounds__(256) void count_wprep_kernel(
    const int* __restrict__ dst1, int E1, int* deg1,
    const int* __restrict__ dst2, int E2, int* deg2,
    const float* __restrict__ W1, const float* __restrict__ W2,
    unsigned short* wfrag)
{
    int b = blockIdx.x;
    if (b < 16) {
        int t = b * 256 + threadIdx.x;     // 4096 threads
        int lane = t & 63;
        int cf   = (t >> 6) & 7;
        int ksm  = (t >> 9) & 3;
        int mat  = t >> 11;
        const float* W = mat ? W2 : W1;
        int g = lane >> 4, c = lane & 15;
        int n = cf * 16 + c;
        unsigned int hi[4], lo[4];
        #pragma unroll
        for (int p = 0; p < 4; ++p) {
            int k0 = ksm * 32 + g * 8 + p * 2;
            float v0 = W[(size_t)k0 * DD + n];
            float v1 = W[(size_t)(k0 + 1) * DD + n];
            split2(v0, v1, hi[p], lo[p]);
        }
        unsigned short* dh = wfrag + (size_t)mat * 32768
                           + ((size_t)(ksm * 8 + cf) * 64 + lane) * 8;
        unsigned short* dl = dh + 16384;
        *(uint4*)dh = make_uint4(hi[0], hi[1], hi[2], hi[3]);
        *(uint4*)dl = make_uint4(lo[0], lo[1], lo[2], lo[3]);
        return;
    }
    int t = (b - 16) * 256 + threadIdx.x;
    if (t < E1) {
        atomicAdd(deg1 + dst1[t], 1);
    } else if (t - E1 < E2) {
        atomicAdd(deg2 + dst2[t - E1], 1);
    }
}

// ---- Phase A: per-block tile sums (raw; scanned redundantly in scanC) ----
__global__ __launch_bounds__(256) void scanA_kernel(
    const int* __restrict__ cur_i, int NI,
    const int* __restrict__ cur_u, int NU,
    int* bsum, int nb0)
{
    int b = blockIdx.x;
    const int* cur;
    int N, base;
    if (b < nb0) { cur = cur_i; N = NI; base = b * SCAN_TILE; }
    else         { cur = cur_u; N = NU; base = (b - nb0) * SCAN_TILE; }
    int t = threadIdx.x;
    int idx0 = base + t * 4;
    int s = 0;
    #pragma unroll
    for (int k = 0; k < 4; ++k) {
        int idx = idx0 + k;
        if (idx < N) s += cur[idx];
    }
    __shared__ int red[256];
    red[t] = s;
    __syncthreads();
    for (int o = 128; o >= 1; o >>= 1) {
        if (t < o) red[t] += red[t + o];
        __syncthreads();
    }
    if (t == 0) bsum[b] = red[0];
}

// ---- Phase C (scanB folded in): every block scans the <=512 raw block
// sums in LDS to get its own offset; block 0 also writes the totals.
__global__ __launch_bounds__(256) void scanC_kernel(
    int* cur_i, int* row_i, int NI,
    int* cur_u, int* row_u, int NU,
    const int* __restrict__ bsum, int nb0, int nb1)
{
    __shared__ int bs[512];
    __shared__ int ps[256];
    __shared__ int sh[256];
    int b = blockIdx.x;
    int t = threadIdx.x;
    int ntot = nb0 + nb1;          // launcher guarantees <= 512

    bs[t]       = (t < ntot)       ? bsum[t]       : 0;
    bs[256 + t] = (256 + t < ntot) ? bsum[256 + t] : 0;
    __syncthreads();
    int b0v = bs[2 * t], b1v = bs[2 * t + 1];
    int pair = b0v + b1v;
    ps[t] = pair;
    __syncthreads();
    for (int o = 1; o < 256; o <<= 1) {
        int u = (t >= o) ? ps[t - o] : 0;
        __syncthreads();
        ps[t] += u;
        __syncthreads();
    }
    int e0 = ps[t] - pair;          // global exclusive prefix at 2t
    __syncthreads();
    bs[2 * t]     = e0;
    bs[2 * t + 1] = e0 + b0v;
    __syncthreads();
    int grand = ps[255];
    int totI  = bs[nb0];            // sum over item segment (nb1 >= 1)
    if (b == 0 && t == 0) {
        row_i[NI] = totI;
        row_u[NU] = grand - totI;
    }
    int off = (b < nb0) ? bs[b] : bs[b] - totI;

    int* cur; int* row;
    int N, base;
    if (b < nb0) { cur = cur_i; row = row_i; N = NI; base = b * SCAN_TILE; }
    else         { cur = cur_u; row = row_u; N = NU; base = (b - nb0) * SCAN_TILE; }
    int idx0 = base + t * 4;
    int v[4];
    int s = 0;
    #pragma unroll
    for (int k = 0; k < 4; ++k) {
        int idx = idx0 + k;
        v[k] = (idx < N) ? cur[idx] : 0;
        s += v[k];
    }
    sh[t] = s;
    __syncthreads();
    for (int o = 1; o < 256; o <<= 1) {
        int u = (t >= o) ? sh[t - o] : 0;
        __syncthreads();
        sh[t] += u;
        __syncthreads();
    }
    int run = off + sh[t] - s;
    #pragma unroll
    for (int k = 0; k < 4; ++k) {
        int idx = idx0 + k;
        if (idx < N) {
            row[idx] = run;
            cur[idx] = run;
            run += v[k];
        }
    }
}

// Fill: scatter PACKED (src, norm) as int2 into dst-grouped order.
__global__ __launch_bounds__(256) void fill_pg_kernel(
    const int* __restrict__ dst1, const int* __restrict__ src1,
    const float* __restrict__ norm1, int E1, int* cur1, int2* esn1,
    const int* __restrict__ dst2, const int* __restrict__ src2,
    const float* __restrict__ norm2, int E2, int* cur2, int2* esn2)
{
    int t = blockIdx.x * 256 + threadIdx.x;
    if (t < E1) {
        int pos = atomicAdd(cur1 + dst1[t], 1);
        esn1[pos] = make_int2(src1[t], __float_as_int(norm1[t]));
    } else if (t - E1 < E2) {
        int e = t - E1;
        int pos = atomicAdd(cur2 + dst2[e], 1);
        esn2[pos] = make_int2(src2[e], __float_as_int(norm2[e]));
    }
}

// ---------------- Fallback: atomic scatter ----------------

__global__ __launch_bounds__(256) void scatter_kernel(
    const float* __restrict__ feat_src,
    const int* __restrict__ src,
    const int* __restrict__ dst,
    const float* __restrict__ norm,
    float* agg,
    float* ssum,
    int E)
{
    int gw = (int)((blockIdx.x * 256u + threadIdx.x) >> 6);
    int lane = threadIdx.x & 63;
    if (gw >= E) return;
    int si = src[gw];
    int di = dst[gw];
    float nv = norm[gw];
    float2 v = *(const float2*)(feat_src + (size_t)si * DD + lane * 2);
    float* ap = agg + (size_t)di * DD + lane * 2;
    unsafeAtomicAdd(ap,     v.x * nv);
    unsafeAtomicAdd(ap + 1, v.y * nv);
    if (lane == 0) unsafeAtomicAdd(ssum + di, nv);
}

// ---------------- Fused gather + MFMA finish (16 rows/block) ----------------
// Phase G: each of 4 waves gathers 4 rows; 6 source-row loads in flight
// (latency-bound random gather -> MLP is the lever). featO read-once ->
// nontemporal, keeps featS resident in L2. __launch_bounds__(256,8) pins
// VGPR<=64 so 8 blocks/CU (32 waves) is preserved.
__global__ __launch_bounds__(256, 8) void fused_kernel(
    const float* __restrict__ feat_user, const float* __restrict__ feat_item,
    const int* __restrict__ row_u, const int2* __restrict__ esnU,
    int NU, int nbU,
    const int* __restrict__ row_i, const int2* __restrict__ esnI, int NI,
    const unsigned short* __restrict__ wfrag,
    const float* __restrict__ b1, const float* __restrict__ b2,
    float* out_base)
{
    __shared__ __align__(16) char smem[FR * 512 * 2];   // 16 KB: Ah | Al
    __shared__ float sst[FR];

    const float *featO, *featS;
    const int *row;
    const int2 *esn;
    float* out;
    int row0, nrows;
    if ((int)blockIdx.x < nbU) {
        featO = feat_user; featS = feat_item; row = row_u; esn = esnU;
        out = out_base; row0 = blockIdx.x * FR; nrows = NU;
    } else {
        featO = feat_item; featS = feat_user; row = row_i; esn = esnI;
        out = out_base + (size_t)NU * DD;
        row0 = (blockIdx.x - nbU) * FR; nrows = NI;
    }

    int t = threadIdx.x;
    int w = t >> 6;
    int lane = t & 63;
    char* pAh = smem;
    char* pAl = smem + FR * 512;

    // ---- Phase G: gather + stage (4 rows per wave, 6-deep load pipe) ----
    for (int rr = 0; rr < 4; ++rr) {
        int r = w * 4 + rr;
        int grow = row0 + r;
        float2 acc = {0.f, 0.f};
        float sn = 0.f;
        f32x2 f2 = {0.f, 0.f};
        if (grow < nrows) {
            f2 = __builtin_nontemporal_load(
                     (const f32x2*)(featO + (size_t)grow * DD + lane * 2));
            int beg = row[grow], end = row[grow + 1];
            int j = beg;
            for (; j + 6 <= end; j += 6) {       // 6 source rows in flight
                int2 e0 = esn[j],     e1 = esn[j + 1], e2 = esn[j + 2];
                int2 e3 = esn[j + 3], e4 = esn[j + 4], e5 = esn[j + 5];
                const float* fb = featS + lane * 2;
                float2 v0 = *(const float2*)(fb + ((size_t)e0.x << 7));
                float2 v1 = *(const float2*)(fb + ((size_t)e1.x << 7));
                float2 v2 = *(const float2*)(fb + ((size_t)e2.x << 7));
                float2 v3 = *(const float2*)(fb + ((size_t)e3.x << 7));
                float2 v4 = *(const float2*)(fb + ((size_t)e4.x << 7));
                float2 v5 = *(const float2*)(fb + ((size_t)e5.x << 7));
                float n0 = __int_as_float(e0.y), n1 = __int_as_float(e1.y);
                float n2 = __int_as_float(e2.y), n3 = __int_as_float(e3.y);
                float n4 = __int_as_float(e4.y), n5 = __int_as_float(e5.y);
                acc.x += n0 * v0.x + n1 * v1.x + n2 * v2.x
                       + n3 * v3.x + n4 * v4.x + n5 * v5.x;
                acc.y += n0 * v0.y + n1 * v1.y + n2 * v2.y
                       + n3 * v3.y + n4 * v4.y + n5 * v5.y;
                sn += n0 + n1 + n2 + n3 + n4 + n5;
            }
            for (; j + 2 <= end; j += 2) {
                int2 e0 = esn[j], e1 = esn[j + 1];
                const float* fb = featS + lane * 2;
                float2 v0 = *(const float2*)(fb + ((size_t)e0.x << 7));
                float2 v1 = *(const float2*)(fb + ((size_t)e1.x << 7));
                float n0 = __int_as_float(e0.y), n1 = __int_as_float(e1.y);
                acc.x += n0 * v0.x + n1 * v1.x;
                acc.y += n0 * v0.y + n1 * v1.y;
                sn += n0 + n1;
            }
            if (j < end) {
                int2 e0 = esn[j];
                float n0 = __int_as_float(e0.y);
                float2 v0 = *(const float2*)(featS + ((size_t)e0.x << 7) + lane * 2);
                acc.x += n0 * v0.x;
                acc.y += n0 * v0.y;
                sn += n0;
            }
        }
        float x0 = f2.x + acc.x, x1 = f2.y + acc.y;
        float y0 = f2.x * acc.x, y1 = f2.y * acc.y;
        unsigned int xh, xl, yh, yl;
        split2(x0, x1, xh, xl);
        split2(y0, y1, yh, yl);
        int swz = (r & 7) << 4;
        int rb = r * 512;
        int xo = rb + ((4 * lane) ^ swz);
        int yo = rb + ((256 + 4 * lane) ^ swz);
        *(unsigned int*)(pAh + xo) = xh;
        *(unsigned int*)(pAl + xo) = xl;
        *(unsigned int*)(pAh + yo) = yh;
        *(unsigned int*)(pAl + yo) = yl;
        if (lane == 0) sst[r] = sn;
    }
    __syncthreads();

    // ---- Phase 2: MFMA over K=256 (8 k-steps of 32) ----
    int r16 = lane & 15, g = lane >> 4;
    f32x4 acc0 = {0.f,0.f,0.f,0.f}, acc1 = {0.f,0.f,0.f,0.f};
    const char* cAh = (const char*)pAh;
    const char* cAl = (const char*)pAl;
    int swzA = (r16 & 7) << 4;
    int ob0 = r16 * 512;

    #pragma unroll 2
    for (int ks = 0; ks < 8; ++ks) {
        int offx = (ks * 64 + g * 16) ^ swzA;
        short8 a0h = *(const short8*)(cAh + ob0 + offx);
        short8 a0l = *(const short8*)(cAl + ob0 + offx);
        int mat = ks >> 2, ksm = ks & 3;
        const unsigned short* ph = wfrag + (size_t)mat * 32768;
        const unsigned short* pl = ph + 16384;
        int bo0 = ((ksm * 8 + w * 2) * 64 + lane) * 8;
        int bo1 = bo0 + 512;
        short8 b0h = *(const short8*)(ph + bo0);
        short8 b0l = *(const short8*)(pl + bo0);
        short8 b1h = *(const short8*)(ph + bo1);
        short8 b1l = *(const short8*)(pl + bo1);
        acc0 = __builtin_amdgcn_mfma_f32_16x16x32_bf16(a0h, b0h, acc0, 0, 0, 0);
        acc0 = __builtin_amdgcn_mfma_f32_16x16x32_bf16(a0h, b0l, acc0, 0, 0, 0);
        acc0 = __builtin_amdgcn_mfma_f32_16x16x32_bf16(a0l, b0h, acc0, 0, 0, 0);
        acc1 = __builtin_amdgcn_mfma_f32_16x16x32_bf16(a0h, b1h, acc1, 0, 0, 0);
        acc1 = __builtin_amdgcn_mfma_f32_16x16x32_bf16(a0h, b1l, acc1, 0, 0, 0);
        acc1 = __builtin_amdgcn_mfma_f32_16x16x32_bf16(a0l, b1h, acc1, 0, 0, 0);
    }
    __syncthreads();

    // ---- Phase 3: h -> LDS (reuse smem as padded f32 buf), epilogue ----
    float* hbuf = (float*)smem;    // FR x HS f32 = 8.7 KB
    #pragma unroll
    for (int j = 0; j < 4; ++j) {
        int rA = g * 4 + j;
        hbuf[rA * HS + (w * 32 + r16)]      = acc0[j];
        hbuf[rA * HS + (w * 32 + 16 + r16)] = acc1[j];
    }
    __syncthreads();

    int c0 = t & 63, c1 = c0 + 64, rg = t >> 6;
    float b1c0 = b1[c0], b1c1 = b1[c1];
    float b2c0 = b2[c0], b2c1 = b2[c1];
    #pragma unroll
    for (int rr = 0; rr < 4; ++rr) {
        int lr = rg * 4 + rr;
        int row_ = row0 + lr;
        if (row_ < nrows) {
            float s = sst[lr];
            float h0 = hbuf[lr * HS + c0] + (1.0f + s) * b1c0 + s * b2c0;
            float h1 = hbuf[lr * HS + c1] + (1.0f + s) * b1c1 + s * b2c1;
            h0 = h0 >= 0.f ? h0 : 0.2f * h0;
            h1 = h1 >= 0.f ? h1 : 0.2f * h1;
            float loc = h0 * h0 + h1 * h1;
            #pragma unroll
            for (int m = 32; m >= 1; m >>= 1) loc += __shfl_xor(loc, m, 64);
            float inv = 1.0f / fmaxf(sqrtf(loc), 1e-12f);
            __builtin_nontemporal_store(h0 * inv, out + (size_t)row_ * DD + c0);
            __builtin_nontemporal_store(h1 * inv, out + (size_t)row_ * DD + c1);
        }
    }
}

// ---------------- fp32 finish (fallback) ----------------

__global__ __launch_bounds__(256) void finish_kernel(
    const float* __restrict__ feat,
    const float* agg,
    const float* __restrict__ ssum,
    const float* __restrict__ W1,
    const float* __restrict__ b1,
    const float* __restrict__ W2,
    const float* __restrict__ b2,
    float* out,
    int nrows)
{
    __shared__ float xs[32][DD];
    __shared__ float ys[32][DD];
    int row0 = blockIdx.x * 32;
    int tid = threadIdx.x;

    for (int i = tid; i < 32 * (DD / 4); i += 256) {
        int r = i >> 5;
        int c4 = (i & 31) * 4;
        int row = row0 + r;
        if (row < nrows) {
            float4 f = *(const float4*)(feat + (size_t)row * DD + c4);
            float4 a = *(const float4*)(agg  + (size_t)row * DD + c4);
            float4 x, y;
            x.x = f.x + a.x; x.y = f.y + a.y; x.z = f.z + a.z; x.w = f.w + a.w;
            y.x = f.x * a.x; y.y = f.y * a.y; y.z = f.z * a.z; y.w = f.w * a.w;
            *(float4*)&xs[r][c4] = x;
            *(float4*)&ys[r][c4] = y;
        }
    }
    __syncthreads();

    int c0 = tid & 63;
    int rg = tid >> 6;
    int c1 = c0 + 64;

    float acc[8][2] = {{0.f,0.f},{0.f,0.f},{0.f,0.f},{0.f,0.f},
                       {0.f,0.f},{0.f,0.f},{0.f,0.f},{0.f,0.f}};
    for (int k = 0; k < DD; k += 4) {
        float w1a[4], w1b[4], w2a[4], w2b[4];
        #pragma unroll
        for (int kk = 0; kk < 4; ++kk) {
            const float* wr1 = W1 + (size_t)(k + kk) * DD;
            const float* wr2 = W2 + (size_t)(k + kk) * DD;
            w1a[kk] = wr1[c0]; w1b[kk] = wr1[c1];
            w2a[kk] = wr2[c0]; w2b[kk] = wr2[c1];
        }
        #pragma unroll
        for (int r = 0; r < 8; ++r) {
            float4 xv = *(const float4*)&xs[rg * 8 + r][k];
            float4 yv = *(const float4*)&ys[rg * 8 + r][k];
            acc[r][0] += xv.x*w1a[0] + xv.y*w1a[1] + xv.z*w1a[2] + xv.w*w1a[3]
                       + yv.x*w2a[0] + yv.y*w2a[1] + yv.z*w2a[2] + yv.w*w2a[3];
            acc[r][1] += xv.x*w1b[0] + xv.y*w1b[1] + xv.z*w1b[2] + xv.w*w1b[3]
                       + yv.x*w2b[0] + yv.y*w2b[1] + yv.z*w2b[2] + yv.w*w2b[3];
        }
    }

    float b1c0 = b1[c0], b1c1 = b1[c1];
    float b2c0 = b2[c0], b2c1 = b2[c1];

    #pragma unroll
    for (int r = 0; r < 8; ++r) {
        int row = row0 + rg * 8 + r;
        if (row < nrows) {
            float s = ssum[row];
            float h0 = acc[r][0] + (1.0f + s) * b1c0 + s * b2c0;
            float h1 = acc[r][1] + (1.0f + s) * b1c1 + s * b2c1;
            h0 = h0 >= 0.f ? h0 : 0.2f * h0;
            h1 = h1 >= 0.f ? h1 : 0.2f * h1;
            float loc = h0 * h0 + h1 * h1;
            #pragma unroll
            for (int m = 32; m >= 1; m >>= 1) loc += __shfl_xor(loc, m, 64);
            float inv = 1.0f / fmaxf(sqrtf(loc), 1e-12f);
            out[(size_t)row * DD + c0] = h0 * inv;
            out[(size_t)row * DD + c1] = h1 * inv;
        }
    }
}

extern "C" void kernel_launch(void* const* d_in, const int* in_sizes, int n_in,
                              void* d_out, int out_size, void* d_ws, size_t ws_size,
                              hipStream_t stream) {
    const float* feat_user = (const float*)d_in[0];
    const float* feat_item = (const float*)d_in[1];
    const float* W1        = (const float*)d_in[2];
    const float* b1        = (const float*)d_in[3];
    const float* W2        = (const float*)d_in[4];
    const float* b2        = (const float*)d_in[5];
    const float* norm_u2i  = (const float*)d_in[6];
    const float* norm_i2u  = (const float*)d_in[7];
    const int* eus = (const int*)d_in[8];
    const int* eud = (const int*)d_in[9];
    const int* eis = (const int*)d_in[10];
    const int* eid = (const int*)d_in[11];

    int NU = in_sizes[0] / DD;
    int NI = in_sizes[1] / DD;
    int E1 = in_sizes[8];
    int E2 = in_sizes[10];
    float* out = (float*)d_out;

    int nb0 = (NI + SCAN_TILE - 1) / SCAN_TILE;
    int nb1 = (NU + SCAN_TILE - 1) / SCAN_TILE;
    int nbU = (NU + FR - 1) / FR;
    int nbI = (NI + FR - 1) / FR;

    size_t wfrag_bytes = 131072;   // 4 planes x 32 KB
    size_t need_pg   = wfrag_bytes + 64 /*align slack*/ +
                       ((size_t)3 * NU + 3 * NI + 2 * E1 + 2 * E2 + 2
                        + nb0 + nb1) * sizeof(int);

    int eb = (int)(((long long)E1 + E2 + 255) / 256);

    if (ws_size >= need_pg && nb0 + nb1 <= 512) {
        // ---- Tier 1: CSR + packed pre-gather + fused gather/MFMA finish ----
        unsigned short* wfrag = (unsigned short*)d_ws;   // 128 KB
        int* cur_i = (int*)((char*)d_ws + wfrag_bytes);  // NI
        int* cur_u = cur_i + NI;            // NU
        int* row_i = cur_u + NU;            // NI+1
        int* row_u = row_i + NI + 1;        // NU+1
        int* pend  = row_u + NU + 1;
        int2* esn1 = (int2*)(((uintptr_t)pend + 15) & ~(uintptr_t)15);  // E1
        int2* esn2 = esn1 + E1;             // E2
        int* bsum  = (int*)(esn2 + E2);     // nb0+nb1 raw tile sums

        hipMemsetAsync(cur_i, 0, (size_t)(NI + NU) * sizeof(int), stream);

        count_wprep_kernel<<<16 + eb, 256, 0, stream>>>(
            eud, E1, cur_i, eid, E2, cur_u, W1, W2, wfrag);
        scanA_kernel<<<nb0 + nb1, 256, 0, stream>>>(cur_i, NI, cur_u, NU,
                                                    bsum, nb0);
        scanC_kernel<<<nb0 + nb1, 256, 0, stream>>>(cur_i, row_i, NI,
                                                    cur_u, row_u, NU,
                                                    bsum, nb0, nb1);
        fill_pg_kernel<<<eb, 256, 0, stream>>>(
            eud, eus, norm_u2i, E1, cur_i, esn1,
            eid, eis, norm_i2u, E2, cur_u, esn2);

        fused_kernel<<<nbU + nbI, 256, 0, stream>>>(
            feat_user, feat_item,
            row_u, esn2, NU, nbU,
            row_i, esn1, NI,
            wfrag, b1, b2, out);
    } else {
        // ---- Fallback: atomic scatter + fp32 finish ----
        float* agg_user = out;
        float* agg_item = out + (size_t)NU * DD;
        float* s_user = (float*)d_ws;
        float* s_item = s_user + NU;

        hipMemsetAsync(out, 0, (size_t)out_size * sizeof(float), stream);
        hipMemsetAsync(d_ws, 0, (size_t)(NU + NI) * sizeof(float), stream);

        int b1n = (int)(((long long)E1 * 64 + 255) / 256);
        scatter_kernel<<<b1n, 256, 0, stream>>>(feat_user, eus, eud, norm_u2i,
                                                agg_item, s_item, E1);
        int b2n = (int)(((long long)E2 * 64 + 255) / 256);
        scatter_kernel<<<b2n, 256, 0, stream>>>(feat_item, eis, eid, norm_i2u,
                                                agg_user, s_user, E2);

        finish_kernel<<<(NU + 31) / 32, 256, 0, stream>>>(
            feat_user, agg_user, s_user, W1, b1, W2, b2, out, NU);
        finish_kernel<<<(NI + 31) / 32, 256, 0, stream>>>(
            feat_item, agg_item, s_item, W1, b1, W2, b2,
            out + (size_t)NU * DD, NI);
    }
}